// Round 3
// baseline (2094.678 us; speedup 1.0000x reference)
//
#include <hip/hip_runtime.h>
#include <hip/hip_bf16.h>

typedef unsigned short b16;
typedef __attribute__((ext_vector_type(8))) unsigned short us8;

#define NN 100000
#define NE 600000

__device__ __forceinline__ float bf2f(b16 u) {
    return __uint_as_float(((unsigned)u) << 16);
}
__device__ __forceinline__ b16 f2bf(float f) {
    unsigned x = __float_as_uint(f);
    return (b16)((x + 0x7fffu + ((x >> 16) & 1u)) >> 16);
}

// typed store/load helpers (hop buffers: fp32 or bf16 storage, fp32 compute)
__device__ __forceinline__ float2 ld2(const float* p) { return *(const float2*)p; }
__device__ __forceinline__ float2 ld2(const b16* p) {
    ushort2 u = *(const ushort2*)p;
    return make_float2(bf2f(u.x), bf2f(u.y));
}
__device__ __forceinline__ void st2(float* p, float2 v) { *(float2*)p = v; }
__device__ __forceinline__ void st2(b16* p, float2 v) {
    ushort2 u;
    u.x = f2bf(v.x);
    u.y = f2bf(v.y);
    *(ushort2*)p = u;
}
__device__ __forceinline__ float4 ld4(const float* p) { return *(const float4*)p; }
__device__ __forceinline__ float4 ld4(const b16* p) {
    ushort4 u = *(const ushort4*)p;
    return make_float4(bf2f(u.x), bf2f(u.y), bf2f(u.z), bf2f(u.w));
}
__device__ __forceinline__ void st4(float* p, float4 v) { *(float4*)p = v; }
__device__ __forceinline__ void st4(b16* p, float4 v) {
    ushort4 u;
    u.x = f2bf(v.x);
    u.y = f2bf(v.y);
    u.z = f2bf(v.z);
    u.w = f2bf(v.w);
    *(ushort4*)p = u;
}
__device__ __forceinline__ void st1(float* p, float v) { *p = v; }
__device__ __forceinline__ void st1(b16* p, float v) { *p = f2bf(v); }

// ---------- dtype detection: flags[0]=1 if float tensors are fp32 (else bf16)
//                              flags[1]=1 if edge_index is int64 (else int32)
__global__ void k_detect(const void* __restrict__ y, const void* __restrict__ ei,
                         int* __restrict__ flags) {
    if (threadIdx.x == 0 && blockIdx.x == 0) {
        const b16* p = (const b16*)y;
        int f32 = 0;
        for (int i = 0; i < 128; ++i) {
            float v = bf2f(p[i]);
            if (!(fabsf(v) < 1e4f)) {  // catches huge AND NaN
                f32 = 1;
                break;
            }
        }
        flags[0] = f32;
        const long long* q = (const long long*)ei;
        int i64 = 1;
        for (int i = 0; i < 4; ++i) {
            long long v = q[i];
            if (v < 0 || v >= NN) i64 = 0;
        }
        flags[1] = i64;
    }
}

// generic float-tensor normalize -> fp32
__global__ void k_cvt(const void* __restrict__ in, float* __restrict__ out, int n,
                      const int* __restrict__ flags) {
    int i = blockIdx.x * blockDim.x + threadIdx.x;
    if (i >= n) return;
    out[i] = flags[0] ? ((const float*)in)[i] : bf2f(((const b16*)in)[i]);
}

// ---------- edge_index normalize ----------
__global__ void k_idx(const void* __restrict__ ei, int* __restrict__ src32,
                      int* __restrict__ dst32, const int* __restrict__ flags) {
    int e = blockIdx.x * blockDim.x + threadIdx.x;
    if (e >= NE) return;
    int s, d;
    if (flags[1]) {
        const long long* p = (const long long*)ei;
        s = (int)p[e];
        d = (int)p[NE + e];
    } else {
        const int* p = (const int*)ei;
        s = p[e];
        d = p[NE + e];
    }
    src32[e] = ((unsigned)s < NN) ? s : 0;
    dst32[e] = ((unsigned)d < NN) ? d : 0;
}

// ---------- degree (weighted) + CSR count ----------
__global__ void k_degcnt(const int* __restrict__ dst, const void* __restrict__ ea,
                         float* __restrict__ deg, int* __restrict__ cnt,
                         const int* __restrict__ flags) {
    int e = blockIdx.x * blockDim.x + threadIdx.x;
    if (e >= NE) return;
    float w = flags[0] ? ((const float*)ea)[e] : bf2f(((const b16*)ea)[e]);
    int d = dst[e];
    unsafeAtomicAdd(&deg[d], w);
    atomicAdd(&cnt[d], 1);
}

__global__ void k_dis(float* deg) {
    int n = blockIdx.x * blockDim.x + threadIdx.x;
    if (n < NN) {
        float d = deg[n];
        deg[n] = (d > 0.f) ? rsqrtf(fmaxf(d, 1e-12f)) : 0.f;
    }
}

// ---------- 3-phase exclusive scan of cnt[NN] -> rowptr[NN+1] ----------
#define SCAN_B 1024
#define SCAN_NB ((NN + SCAN_B - 1) / SCAN_B)  // 98

__global__ __launch_bounds__(SCAN_B) void k_scan1(const int* __restrict__ cnt,
                                                  int* __restrict__ inc,
                                                  int* __restrict__ bsum) {
    __shared__ int s[SCAN_B];
    int i = blockIdx.x * SCAN_B + threadIdx.x;
    s[threadIdx.x] = (i < NN) ? cnt[i] : 0;
    __syncthreads();
    for (int off = 1; off < SCAN_B; off <<= 1) {
        int t = (threadIdx.x >= off) ? s[threadIdx.x - off] : 0;
        __syncthreads();
        s[threadIdx.x] += t;
        __syncthreads();
    }
    if (i < NN) inc[i] = s[threadIdx.x];
    if (threadIdx.x == SCAN_B - 1) bsum[blockIdx.x] = s[SCAN_B - 1];
}

__global__ void k_scan2(int* bsum) {
    if (threadIdx.x == 0 && blockIdx.x == 0) {
        int a = 0;
        for (int i = 0; i < SCAN_NB; ++i) {
            int t = bsum[i];
            bsum[i] = a;
            a += t;
        }
    }
}

__global__ void k_scan3(const int* __restrict__ inc, const int* __restrict__ bsum,
                        int* __restrict__ rowptr) {
    int i = blockIdx.x * blockDim.x + threadIdx.x;
    if (i == 0) rowptr[0] = 0;
    if (i < NN) rowptr[i + 1] = inc[i] + bsum[i / SCAN_B];
}

// ---------- fill CSR ----------
__global__ void k_fill(const int* __restrict__ src, const int* __restrict__ dst,
                       const void* __restrict__ ea, const float* __restrict__ dis,
                       const int* __restrict__ rowptr, int* __restrict__ fill,
                       int* __restrict__ csrc, float* __restrict__ cw,
                       const int* __restrict__ flags) {
    int e = blockIdx.x * blockDim.x + threadIdx.x;
    if (e >= NE) return;
    float a = flags[0] ? ((const float*)ea)[e] : bf2f(((const b16*)ea)[e]);
    int d = dst[e];
    int s = src[e];
    int pos = rowptr[d] + atomicAdd(&fill[d], 1);
    csrc[pos] = s;
    cw[pos] = dis[s] * a * dis[d];
}

// ---------- initial cast y -> X ----------
template <typename T>
__global__ void k_cast(const void* __restrict__ y, T* __restrict__ X,
                       const int* __restrict__ flags) {
    int i = blockIdx.x * blockDim.x + threadIdx.x;
    if (i >= NN * 32) return;
    float4 v;
    if (flags[0]) {
        v = ((const float4*)y)[i];
    } else {
        ushort4 u = ((const ushort4*)y)[i];
        v = make_float4(bf2f(u.x), bf2f(u.y), bf2f(u.z), bf2f(u.w));
    }
    st4(X + 4 * i, v);
}

// ---------- SpMM gather: Hout[n] = sum_{e in row n} w_e * Hin[src_e] ----------
template <typename T>
__global__ __launch_bounds__(256) void k_spmm(const T* __restrict__ Hin,
                                              T* __restrict__ Hout,
                                              const int* __restrict__ rowptr,
                                              const int* __restrict__ csrc,
                                              const float* __restrict__ cw) {
    int gid = blockIdx.x * blockDim.x + threadIdx.x;
    int node = gid >> 6;
    int lane = gid & 63;
    if (node >= NN) return;
    int beg = rowptr[node], end = rowptr[node + 1];
    float2 acc = make_float2(0.f, 0.f);
    for (int i = beg; i < end; ++i) {
        int s = csrc[i];
        float w = cw[i];
        float2 v = ld2(Hin + (size_t)s * 128 + 2 * lane);
        acc.x = fmaf(w, v.x, acc.x);
        acc.y = fmaf(w, v.y, acc.y);
    }
    st2(Hout + (size_t)node * 128 + 2 * lane, acc);
}

// ---------- GEMM: OUT(beta) = H[NNx128] @ W[128xNC] (+bias) ----------
// W staged to LDS as bf16 (error << 2% threshold); H tile staged fp32.
template <int NC, typename T>
__global__ __launch_bounds__(256) void k_gemm(const T* __restrict__ H,
                                              const void* __restrict__ W, int woff,
                                              const float* __restrict__ bias,
                                              float* __restrict__ OUT,
                                              const int* __restrict__ flags, int beta) {
    constexpr int CPT = NC / 8;  // 16 (NC=128) or 8 (NC=64)
    __shared__ float Hs[32 * 132];
    __shared__ b16 Ws[128 * NC];
    const int tid = threadIdx.x;
    const int row0 = blockIdx.x * 32;

    if (flags[0]) {
        const float* Wf = (const float*)W + woff;
        for (int i = tid; i < 128 * NC; i += 256) Ws[i] = f2bf(Wf[i]);
    } else {
        const b16* Wb = (const b16*)W + woff;
        for (int i = tid; i < 128 * NC / 8; i += 256)
            ((us8*)Ws)[i] = ((const us8*)Wb)[i];
    }
    for (int i = tid; i < 32 * 32; i += 256) {
        int r = i >> 5, c = i & 31;
        float4 v = ld4(H + (size_t)(row0 + r) * 128 + 4 * c);
        *(float4*)(Hs + r * 132 + 4 * c) = v;
    }
    __syncthreads();

    const int n = tid >> 3;
    const int c0 = (tid & 7) * CPT;
    float acc[CPT];
#pragma unroll
    for (int j = 0; j < CPT; ++j) acc[j] = 0.f;

    const float* hr = &Hs[n * 132];
    const b16* wp = &Ws[c0];
#pragma unroll 4
    for (int k = 0; k < 128; ++k) {
        float a = hr[k];
        const b16* wr = wp + k * NC;
#pragma unroll
        for (int q = 0; q < CPT / 8; ++q) {
            us8 wv = *(const us8*)(wr + 8 * q);
#pragma unroll
            for (int t = 0; t < 8; ++t)
                acc[8 * q + t] = fmaf(a, bf2f(wv[t]), acc[8 * q + t]);
        }
    }

    float* op = OUT + (size_t)(row0 + n) * NC + c0;
    if (beta) {
#pragma unroll
        for (int j = 0; j < CPT; ++j) op[j] += acc[j];
    } else if (bias) {
#pragma unroll
        for (int j = 0; j < CPT; ++j) op[j] = acc[j] + bias[c0 + j];
    } else {
#pragma unroll
        for (int j = 0; j < CPT; ++j) op[j] = acc[j];
    }
}

// ---------- BatchNorm ----------
__global__ void k_bnsum(const float* __restrict__ OUT, float* __restrict__ gsum,
                        float* __restrict__ gsq, int ncols) {
    int c = threadIdx.x;
    float s = 0.f, s2 = 0.f;
    for (int r = blockIdx.x; r < NN; r += gridDim.x) {
        float v = OUT[(size_t)r * ncols + c];
        s += v;
        s2 += v * v;
    }
    unsafeAtomicAdd(&gsum[c], s);
    unsafeAtomicAdd(&gsq[c], s2);
}

__global__ void k_bnparam(const float* gsum, const float* gsq, const float* g,
                          const float* be, float* scale, float* shift, int ncols) {
    int c = threadIdx.x;
    if (c < ncols) {
        float m = gsum[c] * (1.f / NN);
        float v = gsq[c] * (1.f / NN) - m * m;
        v = fmaxf(v, 0.f);
        float s = rsqrtf(v + 1e-5f) * g[c];
        scale[c] = s;
        shift[c] = be[c] - m * s;
    }
}

template <typename T>
__global__ void k_bnapply(const float* __restrict__ OUT, const float* __restrict__ scale,
                          const float* __restrict__ shift, T* __restrict__ X,
                          void* __restrict__ dout, const int* __restrict__ flags,
                          int cmask, int total) {
    int i = blockIdx.x * blockDim.x + threadIdx.x;
    if (i >= total) return;
    int c = i & cmask;
    float v = fmaf(OUT[i], scale[c], shift[c]);
    v = v > 0.f ? v : 0.01f * v;
    if (dout) {
        if (flags[0])
            ((float*)dout)[i] = v;
        else
            ((b16*)dout)[i] = f2bf(v);
    } else {
        st1(X + i, v);
    }
}

// ---------- driver ----------
struct Bufs {
    int *flags, *src32, *dst32, *cnt, *rowptr, *cscan, *bsum, *csrc;
    float *deg, *cw, *PB, *OUT, *gsum, *gsq, *scale, *shift;
    char *X, *H;
};

// param block offsets (floats)
#define PB_B1 0
#define PB_B2 128
#define PB_G1 256
#define PB_BE1 384
#define PB_G2 512
#define PB_BE2 640
#define PB_G3 768
#define PB_BE3 832
#define PB_SZ 896

template <typename T>
static void run_layers(const Bufs& B, const void* y, const void* W1, const void* W2,
                       const void* W3, void* d_out, hipStream_t stream) {
    T* X = (T*)B.X;
    T* H = (T*)B.H;
    k_cast<T><<<(NN * 32 + 255) / 256, 256, 0, stream>>>(y, X, B.flags);

    auto spmm = [&](const T* in, T* out) {
        k_spmm<T><<<(NN * 64 + 255) / 256, 256, 0, stream>>>(in, out, B.rowptr, B.csrc,
                                                             B.cw);
    };
    auto gemm = [&](int NC, const T* Hin, const void* W, int hop, const float* bias,
                    int beta) {
        if (NC == 128)
            k_gemm<128, T><<<NN / 32, 256, 0, stream>>>(Hin, W, hop * 128 * 128, bias,
                                                        B.OUT, B.flags, beta);
        else
            k_gemm<64, T><<<NN / 32, 256, 0, stream>>>(Hin, W, hop * 128 * 64, bias,
                                                       B.OUT, B.flags, beta);
    };

    auto layer = [&](const void* W, const float* bias, const float* g, const float* be,
                     int NC, bool last) {
        gemm(NC, X, W, 0, bias, 0);
        spmm(X, H);
        gemm(NC, H, W, 1, nullptr, 1);
        spmm(H, X);
        gemm(NC, X, W, 2, nullptr, 1);
        spmm(X, H);
        gemm(NC, H, W, 3, nullptr, 1);

        hipMemsetAsync(B.gsum, 0, NC * 4, stream);
        hipMemsetAsync(B.gsq, 0, NC * 4, stream);
        k_bnsum<<<512, NC, 0, stream>>>(B.OUT, B.gsum, B.gsq, NC);
        k_bnparam<<<1, NC, 0, stream>>>(B.gsum, B.gsq, g, be, B.scale, B.shift, NC);
        int total = NN * NC;
        k_bnapply<T><<<(total + 255) / 256, 256, 0, stream>>>(
            B.OUT, B.scale, B.shift, X, last ? d_out : nullptr, B.flags, NC - 1, total);
    };

    layer(W1, B.PB + PB_B1, B.PB + PB_G1, B.PB + PB_BE1, 128, false);
    layer(W2, B.PB + PB_B2, B.PB + PB_G2, B.PB + PB_BE2, 128, false);
    layer(W3, nullptr, B.PB + PB_G3, B.PB + PB_BE3, 64, true);
}

extern "C" void kernel_launch(void* const* d_in, const int* in_sizes, int n_in,
                              void* d_out, int out_size, void* d_ws, size_t ws_size,
                              hipStream_t stream) {
    const void* y   = d_in[0];
    const void* ei  = d_in[1];
    const void* ea  = d_in[2];
    const void* W1  = d_in[3];
    const void* b1  = d_in[4];
    const void* g1  = d_in[5];
    const void* be1 = d_in[6];
    const void* W2  = d_in[7];
    const void* b2  = d_in[8];
    const void* g2  = d_in[9];
    const void* be2 = d_in[10];
    const void* W3  = d_in[11];
    const void* g3  = d_in[12];
    const void* be3 = d_in[13];

    char* w = (char*)d_ws;
    size_t used = 0;
    auto carve = [&](size_t bytes) -> char* {
        char* p = w + used;
        used += (bytes + 255) & ~(size_t)255;
        return p;
    };

    Bufs B;
    B.flags  = (int*)carve(16);
    B.src32  = (int*)carve((size_t)NE * 4);
    B.dst32  = (int*)carve((size_t)NE * 4);
    B.deg    = (float*)carve((size_t)NN * 4);
    B.cnt    = (int*)carve((size_t)NN * 4);
    B.rowptr = (int*)carve((size_t)(NN + 1) * 4);
    B.cscan  = (int*)carve((size_t)NN * 4);
    B.bsum   = (int*)carve((size_t)SCAN_NB * 4);
    B.csrc   = (int*)carve((size_t)NE * 4);
    B.cw     = (float*)carve((size_t)NE * 4);
    B.PB     = (float*)carve(PB_SZ * 4);
    B.OUT    = (float*)carve((size_t)NN * 128 * 4);
    B.gsum   = (float*)carve(128 * 4);
    B.gsq    = (float*)carve(128 * 4);
    B.scale  = (float*)carve(128 * 4);
    B.shift  = (float*)carve(128 * 4);

    size_t remain = (ws_size > used) ? ws_size - used : 0;
    bool f32hop = remain >= 2 * ((size_t)NN * 128 * 4 + 256);
    size_t hop = (size_t)NN * 128 * (f32hop ? 4 : 2);
    B.X = carve(hop);
    B.H = carve(hop);

    // ----- detection + param normalize -----
    k_detect<<<1, 64, 0, stream>>>(y, ei, B.flags);
    auto cvt = [&](const void* in, float* out, int n) {
        k_cvt<<<(n + 127) / 128, 128, 0, stream>>>(in, out, n, B.flags);
    };
    cvt(b1, B.PB + PB_B1, 128);
    cvt(b2, B.PB + PB_B2, 128);
    cvt(g1, B.PB + PB_G1, 128);
    cvt(be1, B.PB + PB_BE1, 128);
    cvt(g2, B.PB + PB_G2, 128);
    cvt(be2, B.PB + PB_BE2, 128);
    cvt(g3, B.PB + PB_G3, 64);
    cvt(be3, B.PB + PB_BE3, 64);

    // ----- graph prep -----
    k_idx<<<(NE + 255) / 256, 256, 0, stream>>>(ei, B.src32, B.dst32, B.flags);
    hipMemsetAsync(B.deg, 0, (size_t)NN * 4, stream);
    hipMemsetAsync(B.cnt, 0, (size_t)NN * 4, stream);
    k_degcnt<<<(NE + 255) / 256, 256, 0, stream>>>(B.dst32, ea, B.deg, B.cnt, B.flags);
    k_dis<<<(NN + 255) / 256, 256, 0, stream>>>(B.deg);
    k_scan1<<<SCAN_NB, SCAN_B, 0, stream>>>(B.cnt, B.cscan, B.bsum);
    k_scan2<<<1, 64, 0, stream>>>(B.bsum);
    k_scan3<<<(NN + 255) / 256, 256, 0, stream>>>(B.cscan, B.bsum, B.rowptr);
    hipMemsetAsync(B.cnt, 0, (size_t)NN * 4, stream);
    k_fill<<<(NE + 255) / 256, 256, 0, stream>>>(B.src32, B.dst32, ea, B.deg, B.rowptr,
                                                 B.cnt, B.csrc, B.cw, B.flags);

    if (f32hop)
        run_layers<float>(B, y, W1, W2, W3, d_out, stream);
    else
        run_layers<b16>(B, y, W1, W2, W3, d_out, stream);
}

// Round 4
// 1210.247 us; speedup vs baseline: 1.7308x; 1.7308x over previous
//
#include <hip/hip_runtime.h>
#include <hip/hip_bf16.h>

typedef unsigned short b16;
typedef __attribute__((ext_vector_type(8))) unsigned short us8;
typedef __attribute__((ext_vector_type(8))) short short8;   // MFMA A/B frag (8 bf16)
typedef __attribute__((ext_vector_type(4))) float float4v;  // MFMA C/D frag

#define NN 100000
#define NE 600000

__device__ __forceinline__ float bf2f(b16 u) {
    return __uint_as_float(((unsigned)u) << 16);
}
__device__ __forceinline__ b16 f2bf(float f) {
    unsigned x = __float_as_uint(f);
    return (b16)((x + 0x7fffu + ((x >> 16) & 1u)) >> 16);
}

// ---------- dtype detection: flags[0]=1 if float tensors fp32, flags[1]=1 if idx int64
__global__ void k_detect(const void* __restrict__ y, const void* __restrict__ ei,
                         int* __restrict__ flags) {
    if (threadIdx.x == 0 && blockIdx.x == 0) {
        const b16* p = (const b16*)y;
        int f32 = 0;
        for (int i = 0; i < 128; ++i) {
            float v = bf2f(p[i]);
            if (!(fabsf(v) < 1e4f)) { f32 = 1; break; }
        }
        flags[0] = f32;
        const long long* q = (const long long*)ei;
        int i64 = 1;
        for (int i = 0; i < 4; ++i) {
            long long v = q[i];
            if (v < 0 || v >= NN) i64 = 0;
        }
        flags[1] = i64;
    }
}

__global__ void k_cvt(const void* __restrict__ in, float* __restrict__ out, int n,
                      const int* __restrict__ flags) {
    int i = blockIdx.x * blockDim.x + threadIdx.x;
    if (i >= n) return;
    out[i] = flags[0] ? ((const float*)in)[i] : bf2f(((const b16*)in)[i]);
}

// ---------- edge_index normalize ----------
__global__ void k_idx(const void* __restrict__ ei, int* __restrict__ src32,
                      int* __restrict__ dst32, const int* __restrict__ flags) {
    int e = blockIdx.x * blockDim.x + threadIdx.x;
    if (e >= NE) return;
    int s, d;
    if (flags[1]) {
        const long long* p = (const long long*)ei;
        s = (int)p[e];
        d = (int)p[NE + e];
    } else {
        const int* p = (const int*)ei;
        s = p[e];
        d = p[NE + e];
    }
    src32[e] = ((unsigned)s < NN) ? s : 0;
    dst32[e] = ((unsigned)d < NN) ? d : 0;
}

// ---------- degree (weighted) + CSR count ----------
__global__ void k_degcnt(const int* __restrict__ dst, const void* __restrict__ ea,
                         float* __restrict__ deg, int* __restrict__ cnt,
                         const int* __restrict__ flags) {
    int e = blockIdx.x * blockDim.x + threadIdx.x;
    if (e >= NE) return;
    float w = flags[0] ? ((const float*)ea)[e] : bf2f(((const b16*)ea)[e]);
    int d = dst[e];
    unsafeAtomicAdd(&deg[d], w);
    atomicAdd(&cnt[d], 1);
}

__global__ void k_dis(float* deg) {
    int n = blockIdx.x * blockDim.x + threadIdx.x;
    if (n < NN) {
        float d = deg[n];
        deg[n] = (d > 0.f) ? rsqrtf(fmaxf(d, 1e-12f)) : 0.f;
    }
}

// ---------- 3-phase exclusive scan of cnt[NN] -> rowptr[NN+1] ----------
#define SCAN_B 1024
#define SCAN_NB ((NN + SCAN_B - 1) / SCAN_B)

__global__ __launch_bounds__(SCAN_B) void k_scan1(const int* __restrict__ cnt,
                                                  int* __restrict__ inc,
                                                  int* __restrict__ bsum) {
    __shared__ int s[SCAN_B];
    int i = blockIdx.x * SCAN_B + threadIdx.x;
    s[threadIdx.x] = (i < NN) ? cnt[i] : 0;
    __syncthreads();
    for (int off = 1; off < SCAN_B; off <<= 1) {
        int t = (threadIdx.x >= off) ? s[threadIdx.x - off] : 0;
        __syncthreads();
        s[threadIdx.x] += t;
        __syncthreads();
    }
    if (i < NN) inc[i] = s[threadIdx.x];
    if (threadIdx.x == SCAN_B - 1) bsum[blockIdx.x] = s[SCAN_B - 1];
}

__global__ void k_scan2(int* bsum) {
    if (threadIdx.x == 0 && blockIdx.x == 0) {
        int a = 0;
        for (int i = 0; i < SCAN_NB; ++i) {
            int t = bsum[i];
            bsum[i] = a;
            a += t;
        }
    }
}

__global__ void k_scan3(const int* __restrict__ inc, const int* __restrict__ bsum,
                        int* __restrict__ rowptr) {
    int i = blockIdx.x * blockDim.x + threadIdx.x;
    if (i == 0) rowptr[0] = 0;
    if (i < NN) rowptr[i + 1] = inc[i] + bsum[i / SCAN_B];
}

// ---------- fill CSR ----------
__global__ void k_fill(const int* __restrict__ src, const int* __restrict__ dst,
                       const void* __restrict__ ea, const float* __restrict__ dis,
                       const int* __restrict__ rowptr, int* __restrict__ fill,
                       int* __restrict__ csrc, float* __restrict__ cw,
                       const int* __restrict__ flags) {
    int e = blockIdx.x * blockDim.x + threadIdx.x;
    if (e >= NE) return;
    float a = flags[0] ? ((const float*)ea)[e] : bf2f(((const b16*)ea)[e]);
    int d = dst[e];
    int s = src[e];
    int pos = rowptr[d] + atomicAdd(&fill[d], 1);
    csrc[pos] = s;
    cw[pos] = dis[s] * a * dis[d];
}

// ---------- pack W (fp32/bf16 [512][NC]) into B-fragment order ----------
// Wp[((ks*CT + ct)*64 + lane)*8 + j] = bf16(W[32*ks + (lane>>4)*8 + j][16*ct + (lane&15)])
__global__ void k_pack(const void* __restrict__ W, b16* __restrict__ Wp, int NC,
                       const int* __restrict__ flags) {
    int f = blockIdx.x * blockDim.x + threadIdx.x;
    int total = 512 * NC / 8;
    if (f >= total) return;
    int lane = f & 63;
    int rest = f >> 6;
    int CT = NC >> 4;
    int ct = rest % CT, ks = rest / CT;
    int k0 = 32 * ks + (lane >> 4) * 8;
    int col = 16 * ct + (lane & 15);
    us8 v;
#pragma unroll
    for (int j = 0; j < 8; ++j) {
        float x = flags[0] ? ((const float*)W)[(size_t)(k0 + j) * NC + col]
                           : bf2f(((const b16*)W)[(size_t)(k0 + j) * NC + col]);
        v[j] = f2bf(x);
    }
    *(us8*)&Wp[(size_t)f * 8] = v;
}

// ---------- initial cast y -> XC cols [0,128) (bf16, row stride 512) ----------
__global__ void k_cast(const void* __restrict__ y, b16* __restrict__ XC,
                       const int* __restrict__ flags) {
    int i = blockIdx.x * blockDim.x + threadIdx.x;
    if (i >= NN * 32) return;
    int row = i >> 5, cg = i & 31;
    float4 v;
    if (flags[0]) {
        v = ((const float4*)y)[i];
    } else {
        ushort4 u = ((const ushort4*)y)[i];
        v = make_float4(bf2f(u.x), bf2f(u.y), bf2f(u.z), bf2f(u.w));
    }
    ushort4 o;
    o.x = f2bf(v.x); o.y = f2bf(v.y); o.z = f2bf(v.z); o.w = f2bf(v.w);
    *(ushort4*)&XC[(size_t)row * 512 + 4 * cg] = o;
}

// ---------- SpMM gather within XC: cols [ci,ci+128) -> cols [co,co+128) ----------
__global__ __launch_bounds__(256) void k_spmm(b16* __restrict__ XC, int ci, int co,
                                              const int* __restrict__ rowptr,
                                              const int* __restrict__ csrc,
                                              const float* __restrict__ cw) {
    int gid = blockIdx.x * blockDim.x + threadIdx.x;
    int node = gid >> 6;
    int lane = gid & 63;
    if (node >= NN) return;
    int beg = rowptr[node], end = rowptr[node + 1];
    float2 acc = make_float2(0.f, 0.f);
    for (int i = beg; i < end; ++i) {
        int s = csrc[i];
        float w = cw[i];
        ushort2 u = *(const ushort2*)&XC[(size_t)s * 512 + ci + 2 * lane];
        acc.x = fmaf(w, bf2f(u.x), acc.x);
        acc.y = fmaf(w, bf2f(u.y), acc.y);
    }
    ushort2 o;
    o.x = f2bf(acc.x);
    o.y = f2bf(acc.y);
    *(ushort2*)&XC[(size_t)node * 512 + co + 2 * lane] = o;
}

// ---------- MFMA GEMM: OUT[NN x NC] = XC[NN x 512](bf16) @ Wp (+bias) ----------
template <int NC>
__global__ __launch_bounds__(256) void k_mgemm(const b16* __restrict__ XC,
                                               const b16* __restrict__ Wp,
                                               const float* __restrict__ bias,
                                               float* __restrict__ OUT) {
    constexpr int CT = NC / 16;       // col tiles
    __shared__ b16 As[128 * 40];      // 128 rows x 32 k, stride 40 (80B: 16B-aligned frags)
    __shared__ b16 Bs[CT * 512];      // one k-step of packed W
    const int tid = threadIdx.x;
    const int wave = tid >> 6;
    const int lane = tid & 63;
    const int row0 = blockIdx.x * 128;
    const int quad = lane >> 4;
    const int l15 = lane & 15;

    float4v acc[2][CT];
#pragma unroll
    for (int rt = 0; rt < 2; ++rt)
#pragma unroll
        for (int ct = 0; ct < CT; ++ct) acc[rt][ct] = (float4v)(0.f);

    const int arow = tid >> 1;              // 0..127
    const int apart = tid & 1;              // 16-short half
    int grow = row0 + arow;
    if (grow >= NN) grow = NN - 1;          // clamp: dead rows never stored
    const b16* gA = XC + (size_t)grow * 512 + apart * 16;
    b16* lA = As + arow * 40 + apart * 16;

    for (int ks = 0; ks < 16; ++ks) {
        // stage A tile (128 x 32)
        us8 a0 = *(const us8*)(gA + 32 * ks);
        us8 a1 = *(const us8*)(gA + 32 * ks + 8);
        *(us8*)lA = a0;
        *(us8*)(lA + 8) = a1;
        // stage B k-step (CT*512 shorts, contiguous)
        const us8* gB = (const us8*)(Wp + (size_t)ks * CT * 512);
#pragma unroll
        for (int q = 0; q < CT * 64 / 256; ++q)
            ((us8*)Bs)[q * 256 + tid] = gB[q * 256 + tid];
        __syncthreads();

        short8 af[2], bf[CT];
#pragma unroll
        for (int rt = 0; rt < 2; ++rt)
            af[rt] = *(const short8*)&As[(32 * wave + 16 * rt + l15) * 40 + quad * 8];
#pragma unroll
        for (int ct = 0; ct < CT; ++ct)
            bf[ct] = *(const short8*)&Bs[ct * 512 + lane * 8];
#pragma unroll
        for (int rt = 0; rt < 2; ++rt)
#pragma unroll
            for (int ct = 0; ct < CT; ++ct)
                acc[rt][ct] = __builtin_amdgcn_mfma_f32_16x16x32_bf16(
                    af[rt], bf[ct], acc[rt][ct], 0, 0, 0);
        __syncthreads();
    }

    // epilogue: C/D layout col=lane&15, row=(lane>>4)*4+reg
#pragma unroll
    for (int rt = 0; rt < 2; ++rt) {
#pragma unroll
        for (int ct = 0; ct < CT; ++ct) {
            int col = 16 * ct + l15;
            float bv = bias ? bias[col] : 0.f;
#pragma unroll
            for (int r = 0; r < 4; ++r) {
                int row = row0 + 32 * wave + 16 * rt + quad * 4 + r;
                if (row < NN) OUT[(size_t)row * NC + col] = acc[rt][ct][r] + bv;
            }
        }
    }
}

// ---------- BatchNorm ----------
__global__ void k_bnsum(const float* __restrict__ OUT, float* __restrict__ gsum,
                        float* __restrict__ gsq, int ncols) {
    int c = threadIdx.x;
    float s = 0.f, s2 = 0.f;
    for (int r = blockIdx.x; r < NN; r += gridDim.x) {
        float v = OUT[(size_t)r * ncols + c];
        s += v;
        s2 += v * v;
    }
    unsafeAtomicAdd(&gsum[c], s);
    unsafeAtomicAdd(&gsq[c], s2);
}

__global__ void k_bnparam(const float* gsum, const float* gsq, const float* g,
                          const float* be, float* scale, float* shift, int ncols) {
    int c = threadIdx.x;
    if (c < ncols) {
        float m = gsum[c] * (1.f / NN);
        float v = gsq[c] * (1.f / NN) - m * m;
        v = fmaxf(v, 0.f);
        float s = rsqrtf(v + 1e-5f) * g[c];
        scale[c] = s;
        shift[c] = be[c] - m * s;
    }
}

// layers 1,2: write bf16 into XC cols [0,128)
__global__ void k_bnapply_mid(const float* __restrict__ OUT,
                              const float* __restrict__ scale,
                              const float* __restrict__ shift, b16* __restrict__ XC) {
    int i = blockIdx.x * blockDim.x + threadIdx.x;  // handles 2 cols
    if (i >= NN * 64) return;
    int row = i >> 6, c = (i & 63) * 2;
    float2 v = *(const float2*)&OUT[(size_t)row * 128 + c];
    float a = fmaf(v.x, scale[c], shift[c]);
    float b = fmaf(v.y, scale[c + 1], shift[c + 1]);
    a = a > 0.f ? a : 0.01f * a;
    b = b > 0.f ? b : 0.01f * b;
    ushort2 o;
    o.x = f2bf(a);
    o.y = f2bf(b);
    *(ushort2*)&XC[(size_t)row * 512 + c] = o;
}

// layer 3: write d_out (fp32 or bf16 per flag), NC=64
__global__ void k_bnapply_last(const float* __restrict__ OUT,
                               const float* __restrict__ scale,
                               const float* __restrict__ shift, void* __restrict__ dout,
                               const int* __restrict__ flags) {
    int i = blockIdx.x * blockDim.x + threadIdx.x;
    if (i >= NN * 64) return;
    int c = i & 63;
    float v = fmaf(OUT[i], scale[c], shift[c]);
    v = v > 0.f ? v : 0.01f * v;
    if (flags[0])
        ((float*)dout)[i] = v;
    else
        ((b16*)dout)[i] = f2bf(v);
}

// ---------- driver ----------
#define PB_B1 0
#define PB_B2 128
#define PB_G1 256
#define PB_BE1 384
#define PB_G2 512
#define PB_BE2 640
#define PB_G3 768
#define PB_BE3 832
#define PB_SZ 896

extern "C" void kernel_launch(void* const* d_in, const int* in_sizes, int n_in,
                              void* d_out, int out_size, void* d_ws, size_t ws_size,
                              hipStream_t stream) {
    const void* y   = d_in[0];
    const void* ei  = d_in[1];
    const void* ea  = d_in[2];
    const void* W1  = d_in[3];
    const void* b1  = d_in[4];
    const void* g1  = d_in[5];
    const void* be1 = d_in[6];
    const void* W2  = d_in[7];
    const void* b2  = d_in[8];
    const void* g2  = d_in[9];
    const void* be2 = d_in[10];
    const void* W3  = d_in[11];
    const void* g3  = d_in[12];
    const void* be3 = d_in[13];

    char* w = (char*)d_ws;
    size_t used = 0;
    auto carve = [&](size_t bytes) -> char* {
        char* p = w + used;
        used += (bytes + 255) & ~(size_t)255;
        return p;
    };

    int* flags   = (int*)carve(16);
    int* src32   = (int*)carve((size_t)NE * 4);
    int* dst32   = (int*)carve((size_t)NE * 4);
    float* deg   = (float*)carve((size_t)NN * 4);
    int* cnt     = (int*)carve((size_t)NN * 4);
    int* rowptr  = (int*)carve((size_t)(NN + 1) * 4);
    int* cscan   = (int*)carve((size_t)NN * 4);
    int* bsum    = (int*)carve((size_t)SCAN_NB * 4);
    int* csrc    = (int*)carve((size_t)NE * 4);
    float* cw    = (float*)carve((size_t)NE * 4);
    float* PB    = (float*)carve(PB_SZ * 4);
    b16* Wp1     = (b16*)carve((size_t)512 * 128 * 2);
    b16* Wp2     = (b16*)carve((size_t)512 * 128 * 2);
    b16* Wp3     = (b16*)carve((size_t)512 * 64 * 2);
    float* OUT   = (float*)carve((size_t)NN * 128 * 4);
    float* gsum  = (float*)carve(128 * 4);
    float* gsq   = (float*)carve(128 * 4);
    float* scale = (float*)carve(128 * 4);
    float* shift = (float*)carve(128 * 4);
    b16* XC      = (b16*)carve((size_t)NN * 512 * 2);

    // ----- detection + param normalize + weight pack -----
    k_detect<<<1, 64, 0, stream>>>(y, ei, flags);
    auto cvt = [&](const void* in, float* out, int n) {
        k_cvt<<<(n + 127) / 128, 128, 0, stream>>>(in, out, n, flags);
    };
    cvt(b1, PB + PB_B1, 128);
    cvt(b2, PB + PB_B2, 128);
    cvt(g1, PB + PB_G1, 128);
    cvt(be1, PB + PB_BE1, 128);
    cvt(g2, PB + PB_G2, 128);
    cvt(be2, PB + PB_BE2, 128);
    cvt(g3, PB + PB_G3, 64);
    cvt(be3, PB + PB_BE3, 64);
    k_pack<<<(512 * 128 / 8 + 255) / 256, 256, 0, stream>>>(W1, Wp1, 128, flags);
    k_pack<<<(512 * 128 / 8 + 255) / 256, 256, 0, stream>>>(W2, Wp2, 128, flags);
    k_pack<<<(512 * 64 / 8 + 255) / 256, 256, 0, stream>>>(W3, Wp3, 64, flags);

    // ----- graph prep -----
    k_idx<<<(NE + 255) / 256, 256, 0, stream>>>(ei, src32, dst32, flags);
    hipMemsetAsync(deg, 0, (size_t)NN * 4, stream);
    hipMemsetAsync(cnt, 0, (size_t)NN * 4, stream);
    k_degcnt<<<(NE + 255) / 256, 256, 0, stream>>>(dst32, ea, deg, cnt, flags);
    k_dis<<<(NN + 255) / 256, 256, 0, stream>>>(deg);
    k_scan1<<<SCAN_NB, SCAN_B, 0, stream>>>(cnt, cscan, bsum);
    k_scan2<<<1, 64, 0, stream>>>(bsum);
    k_scan3<<<(NN + 255) / 256, 256, 0, stream>>>(cscan, bsum, rowptr);
    hipMemsetAsync(cnt, 0, (size_t)NN * 4, stream);
    k_fill<<<(NE + 255) / 256, 256, 0, stream>>>(src32, dst32, ea, deg, rowptr, cnt,
                                                 csrc, cw, flags);

    // ----- layers -----
    k_cast<<<(NN * 32 + 255) / 256, 256, 0, stream>>>(y, XC, flags);

    auto spmm = [&](int ci, int co) {
        k_spmm<<<(NN * 64 + 255) / 256, 256, 0, stream>>>(XC, ci, co, rowptr, csrc, cw);
    };
    const int gemm_grid = (NN + 127) / 128;

    auto layer = [&](const b16* Wp, const float* bias, const float* g, const float* be,
                     int NC, bool last) {
        spmm(0, 128);
        spmm(128, 256);
        spmm(256, 384);
        if (NC == 128)
            k_mgemm<128><<<gemm_grid, 256, 0, stream>>>(XC, Wp, bias, OUT);
        else
            k_mgemm<64><<<gemm_grid, 256, 0, stream>>>(XC, Wp, bias, OUT);
        hipMemsetAsync(gsum, 0, NC * 4, stream);
        hipMemsetAsync(gsq, 0, NC * 4, stream);
        k_bnsum<<<512, NC, 0, stream>>>(OUT, gsum, gsq, NC);
        k_bnparam<<<1, NC, 0, stream>>>(gsum, gsq, g, be, scale, shift, NC);
        if (last)
            k_bnapply_last<<<(NN * 64 + 255) / 256, 256, 0, stream>>>(OUT, scale, shift,
                                                                      d_out, flags);
        else
            k_bnapply_mid<<<(NN * 64 + 255) / 256, 256, 0, stream>>>(OUT, scale, shift,
                                                                     XC);
    };

    layer(Wp1, PB + PB_B1, PB + PB_G1, PB + PB_BE1, 128, false);
    layer(Wp2, PB + PB_B2, PB + PB_G2, PB + PB_BE2, 128, false);
    layer(Wp3, nullptr, PB + PB_G3, PB + PB_BE3, 64, true);
}

// Round 5
// 835.643 us; speedup vs baseline: 2.5067x; 1.4483x over previous
//
#include <hip/hip_runtime.h>
#include <hip/hip_bf16.h>

typedef unsigned short b16;
typedef __attribute__((ext_vector_type(8))) unsigned short us8;
typedef __attribute__((ext_vector_type(8))) short short8;   // MFMA A/B frag (8 bf16)
typedef __attribute__((ext_vector_type(4))) float float4v;  // MFMA C/D frag

#define NN 100000
#define NE 600000

__device__ __forceinline__ float bf2f(b16 u) {
    return __uint_as_float(((unsigned)u) << 16);
}
__device__ __forceinline__ b16 f2bf(float f) {
    unsigned x = __float_as_uint(f);
    return (b16)((x + 0x7fffu + ((x >> 16) & 1u)) >> 16);
}

// ---------- dtype detection: flags[0]=1 if float tensors fp32, flags[1]=1 if idx int64
__global__ void k_detect(const void* __restrict__ y, const void* __restrict__ ei,
                         int* __restrict__ flags) {
    if (threadIdx.x == 0 && blockIdx.x == 0) {
        const b16* p = (const b16*)y;
        int f32 = 0;
        for (int i = 0; i < 128; ++i) {
            float v = bf2f(p[i]);
            if (!(fabsf(v) < 1e4f)) { f32 = 1; break; }
        }
        flags[0] = f32;
        const long long* q = (const long long*)ei;
        int i64 = 1;
        for (int i = 0; i < 4; ++i) {
            long long v = q[i];
            if (v < 0 || v >= NN) i64 = 0;
        }
        flags[1] = i64;
    }
}

__global__ void k_cvt(const void* __restrict__ in, float* __restrict__ out, int n,
                      const int* __restrict__ flags) {
    int i = blockIdx.x * blockDim.x + threadIdx.x;
    if (i >= n) return;
    out[i] = flags[0] ? ((const float*)in)[i] : bf2f(((const b16*)in)[i]);
}

// ---------- edge_index normalize ----------
__global__ void k_idx(const void* __restrict__ ei, int* __restrict__ src32,
                      int* __restrict__ dst32, const int* __restrict__ flags) {
    int e = blockIdx.x * blockDim.x + threadIdx.x;
    if (e >= NE) return;
    int s, d;
    if (flags[1]) {
        const long long* p = (const long long*)ei;
        s = (int)p[e];
        d = (int)p[NE + e];
    } else {
        const int* p = (const int*)ei;
        s = p[e];
        d = p[NE + e];
    }
    src32[e] = ((unsigned)s < NN) ? s : 0;
    dst32[e] = ((unsigned)d < NN) ? d : 0;
}

// ---------- degree (weighted) + CSR count ----------
__global__ void k_degcnt(const int* __restrict__ dst, const void* __restrict__ ea,
                         float* __restrict__ deg, int* __restrict__ cnt,
                         const int* __restrict__ flags) {
    int e = blockIdx.x * blockDim.x + threadIdx.x;
    if (e >= NE) return;
    float w = flags[0] ? ((const float*)ea)[e] : bf2f(((const b16*)ea)[e]);
    int d = dst[e];
    unsafeAtomicAdd(&deg[d], w);
    atomicAdd(&cnt[d], 1);
}

__global__ void k_dis(float* deg) {
    int n = blockIdx.x * blockDim.x + threadIdx.x;
    if (n < NN) {
        float d = deg[n];
        deg[n] = (d > 0.f) ? rsqrtf(fmaxf(d, 1e-12f)) : 0.f;
    }
}

// ---------- 3-phase exclusive scan of cnt[NN] -> rowptr[NN+1] ----------
#define SCAN_B 1024
#define SCAN_NB ((NN + SCAN_B - 1) / SCAN_B)

__global__ __launch_bounds__(SCAN_B) void k_scan1(const int* __restrict__ cnt,
                                                  int* __restrict__ inc,
                                                  int* __restrict__ bsum) {
    __shared__ int s[SCAN_B];
    int i = blockIdx.x * SCAN_B + threadIdx.x;
    s[threadIdx.x] = (i < NN) ? cnt[i] : 0;
    __syncthreads();
    for (int off = 1; off < SCAN_B; off <<= 1) {
        int t = (threadIdx.x >= off) ? s[threadIdx.x - off] : 0;
        __syncthreads();
        s[threadIdx.x] += t;
        __syncthreads();
    }
    if (i < NN) inc[i] = s[threadIdx.x];
    if (threadIdx.x == SCAN_B - 1) bsum[blockIdx.x] = s[SCAN_B - 1];
}

__global__ void k_scan2(int* bsum) {
    if (threadIdx.x == 0 && blockIdx.x == 0) {
        int a = 0;
        for (int i = 0; i < SCAN_NB; ++i) {
            int t = bsum[i];
            bsum[i] = a;
            a += t;
        }
    }
}

__global__ void k_scan3(const int* __restrict__ inc, const int* __restrict__ bsum,
                        int* __restrict__ rowptr) {
    int i = blockIdx.x * blockDim.x + threadIdx.x;
    if (i == 0) rowptr[0] = 0;
    if (i < NN) rowptr[i + 1] = inc[i] + bsum[i / SCAN_B];
}

// ---------- fill CSR ----------
__global__ void k_fill(const int* __restrict__ src, const int* __restrict__ dst,
                       const void* __restrict__ ea, const float* __restrict__ dis,
                       const int* __restrict__ rowptr, int* __restrict__ fill,
                       int* __restrict__ csrc, float* __restrict__ cw,
                       const int* __restrict__ flags) {
    int e = blockIdx.x * blockDim.x + threadIdx.x;
    if (e >= NE) return;
    float a = flags[0] ? ((const float*)ea)[e] : bf2f(((const b16*)ea)[e]);
    int d = dst[e];
    int s = src[e];
    int pos = rowptr[d] + atomicAdd(&fill[d], 1);
    csrc[pos] = s;
    cw[pos] = dis[s] * a * dis[d];
}

// ---------- pack W (fp32/bf16 [512][NC]) into B-fragment order ----------
__global__ void k_pack(const void* __restrict__ W, b16* __restrict__ Wp, int NC,
                       const int* __restrict__ flags) {
    int f = blockIdx.x * blockDim.x + threadIdx.x;
    int total = 512 * NC / 8;
    if (f >= total) return;
    int lane = f & 63;
    int rest = f >> 6;
    int CT = NC >> 4;
    int ct = rest % CT, ks = rest / CT;
    int k0 = 32 * ks + (lane >> 4) * 8;
    int col = 16 * ct + (lane & 15);
    us8 v;
#pragma unroll
    for (int j = 0; j < 8; ++j) {
        float x = flags[0] ? ((const float*)W)[(size_t)(k0 + j) * NC + col]
                           : bf2f(((const b16*)W)[(size_t)(k0 + j) * NC + col]);
        v[j] = f2bf(x);
    }
    *(us8*)&Wp[(size_t)f * 8] = v;
}

// ---------- initial cast y -> XC cols [0,128) (bf16, row stride 512) ----------
__global__ void k_cast(const void* __restrict__ y, b16* __restrict__ XC,
                       const int* __restrict__ flags) {
    int i = blockIdx.x * blockDim.x + threadIdx.x;
    if (i >= NN * 32) return;
    int row = i >> 5, cg = i & 31;
    float4 v;
    if (flags[0]) {
        v = ((const float4*)y)[i];
    } else {
        ushort4 u = ((const ushort4*)y)[i];
        v = make_float4(bf2f(u.x), bf2f(u.y), bf2f(u.z), bf2f(u.w));
    }
    ushort4 o;
    o.x = f2bf(v.x); o.y = f2bf(v.y); o.z = f2bf(v.z); o.w = f2bf(v.w);
    *(ushort4*)&XC[(size_t)row * 512 + 4 * cg] = o;
}

// ---------- SpMM gather: cols [ci,ci+128) -> [co,co+128) ----------
// wave = 1 node; half-wave = 1 edge (32 lanes x ushort4 = 256B row segment);
// unroll x2 -> up to 4 edges (1KB) in flight per wave.
__global__ __launch_bounds__(256) void k_spmm(b16* __restrict__ XC, int ci, int co,
                                              const int* __restrict__ rowptr,
                                              const int* __restrict__ csrc,
                                              const float* __restrict__ cw) {
    int gid = blockIdx.x * blockDim.x + threadIdx.x;
    int node = gid >> 6;
    if (node >= NN) return;
    int lane = gid & 63;
    int half = lane >> 5;
    int l31 = lane & 31;
    int beg = rowptr[node], end = rowptr[node + 1];

    float4 a0 = make_float4(0.f, 0.f, 0.f, 0.f);
    float4 a1 = make_float4(0.f, 0.f, 0.f, 0.f);
    int i = beg;
    for (; i + 3 < end; i += 4) {
        int e0 = i + half, e1 = i + 2 + half;
        int s0 = csrc[e0];
        float w0 = cw[e0];
        int s1 = csrc[e1];
        float w1 = cw[e1];
        ushort4 u0 = *(const ushort4*)&XC[(size_t)s0 * 512 + ci + 4 * l31];
        ushort4 u1 = *(const ushort4*)&XC[(size_t)s1 * 512 + ci + 4 * l31];
        a0.x = fmaf(w0, bf2f(u0.x), a0.x);
        a0.y = fmaf(w0, bf2f(u0.y), a0.y);
        a0.z = fmaf(w0, bf2f(u0.z), a0.z);
        a0.w = fmaf(w0, bf2f(u0.w), a0.w);
        a1.x = fmaf(w1, bf2f(u1.x), a1.x);
        a1.y = fmaf(w1, bf2f(u1.y), a1.y);
        a1.z = fmaf(w1, bf2f(u1.z), a1.z);
        a1.w = fmaf(w1, bf2f(u1.w), a1.w);
    }
    for (; i < end; i += 2) {
        bool act = (half == 0) || (i + 1 < end);
        int ee = act ? (i + half) : i;
        float w = act ? cw[ee] : 0.f;
        int s = csrc[ee];
        ushort4 u = *(const ushort4*)&XC[(size_t)s * 512 + ci + 4 * l31];
        a0.x = fmaf(w, bf2f(u.x), a0.x);
        a0.y = fmaf(w, bf2f(u.y), a0.y);
        a0.z = fmaf(w, bf2f(u.z), a0.z);
        a0.w = fmaf(w, bf2f(u.w), a0.w);
    }
    a0.x += a1.x;
    a0.y += a1.y;
    a0.z += a1.z;
    a0.w += a1.w;
    a0.x += __shfl_xor(a0.x, 32);
    a0.y += __shfl_xor(a0.y, 32);
    a0.z += __shfl_xor(a0.z, 32);
    a0.w += __shfl_xor(a0.w, 32);
    if (half == 0) {
        ushort4 o;
        o.x = f2bf(a0.x);
        o.y = f2bf(a0.y);
        o.z = f2bf(a0.z);
        o.w = f2bf(a0.w);
        *(ushort4*)&XC[(size_t)node * 512 + co + 4 * l31] = o;
    }
}

// ---------- MFMA GEMM + fused BN-stat epilogue ----------
// OUT[NN x NC] = XC[NN x 512](bf16) @ Wp (+bias); per-block col sums/sumsq -> gsum/gsq
template <int NC>
__global__ __launch_bounds__(256) void k_mgemm(const b16* __restrict__ XC,
                                               const b16* __restrict__ Wp,
                                               const float* __restrict__ bias,
                                               float* __restrict__ OUT,
                                               float* __restrict__ gsum,
                                               float* __restrict__ gsq) {
    constexpr int CT = NC / 16;
    __shared__ b16 As[128 * 40];
    __shared__ b16 Bs[CT * 512];
    __shared__ float csum[NC], csq[NC];
    const int tid = threadIdx.x;
    const int wave = tid >> 6;
    const int lane = tid & 63;
    const int row0 = blockIdx.x * 128;
    const int quad = lane >> 4;
    const int l15 = lane & 15;

    float4v acc[2][CT];
#pragma unroll
    for (int rt = 0; rt < 2; ++rt)
#pragma unroll
        for (int ct = 0; ct < CT; ++ct) acc[rt][ct] = (float4v)(0.f);
    for (int i = tid; i < NC; i += 256) {
        csum[i] = 0.f;
        csq[i] = 0.f;
    }

    const int arow = tid >> 1;
    const int apart = tid & 1;
    int grow = row0 + arow;
    if (grow >= NN) grow = NN - 1;  // clamp; dead rows excluded from store/stats
    const b16* gA = XC + (size_t)grow * 512 + apart * 16;
    b16* lA = As + arow * 40 + apart * 16;

    for (int ks = 0; ks < 16; ++ks) {
        us8 a0 = *(const us8*)(gA + 32 * ks);
        us8 a1 = *(const us8*)(gA + 32 * ks + 8);
        *(us8*)lA = a0;
        *(us8*)(lA + 8) = a1;
        const us8* gB = (const us8*)(Wp + (size_t)ks * CT * 512);
#pragma unroll
        for (int q = 0; q < CT * 64 / 256; ++q)
            ((us8*)Bs)[q * 256 + tid] = gB[q * 256 + tid];
        __syncthreads();

        short8 af[2], bf[CT];
#pragma unroll
        for (int rt = 0; rt < 2; ++rt)
            af[rt] = *(const short8*)&As[(32 * wave + 16 * rt + l15) * 40 + quad * 8];
#pragma unroll
        for (int ct = 0; ct < CT; ++ct)
            bf[ct] = *(const short8*)&Bs[ct * 512 + lane * 8];
#pragma unroll
        for (int rt = 0; rt < 2; ++rt)
#pragma unroll
            for (int ct = 0; ct < CT; ++ct)
                acc[rt][ct] = __builtin_amdgcn_mfma_f32_16x16x32_bf16(
                    af[rt], bf[ct], acc[rt][ct], 0, 0, 0);
        __syncthreads();
    }

    // epilogue: store + per-block BN stats (C/D: col=lane&15, row=quad*4+reg)
#pragma unroll
    for (int rt = 0; rt < 2; ++rt) {
#pragma unroll
        for (int ct = 0; ct < CT; ++ct) {
            int col = 16 * ct + l15;
            float bv = bias ? bias[col] : 0.f;
            float s = 0.f, sq = 0.f;
#pragma unroll
            for (int r = 0; r < 4; ++r) {
                int row = row0 + 32 * wave + 16 * rt + quad * 4 + r;
                if (row < NN) {
                    float v = acc[rt][ct][r] + bv;
                    OUT[(size_t)row * NC + col] = v;
                    s += v;
                    sq += v * v;
                }
            }
            s += __shfl_xor(s, 16);
            s += __shfl_xor(s, 32);
            sq += __shfl_xor(sq, 16);
            sq += __shfl_xor(sq, 32);
            if (quad == 0) {
                atomicAdd(&csum[col], s);
                atomicAdd(&csq[col], sq);
            }
        }
    }
    __syncthreads();
    for (int i = tid; i < NC; i += 256) {
        unsafeAtomicAdd(&gsum[i], csum[i]);
        unsafeAtomicAdd(&gsq[i], csq[i]);
    }
}

// ---------- BatchNorm params ----------
__global__ void k_bnparam(const float* gsum, const float* gsq, const float* g,
                          const float* be, float* scale, float* shift, int ncols) {
    int c = threadIdx.x;
    if (c < ncols) {
        float m = gsum[c] * (1.f / NN);
        float v = gsq[c] * (1.f / NN) - m * m;
        v = fmaxf(v, 0.f);
        float s = rsqrtf(v + 1e-5f) * g[c];
        scale[c] = s;
        shift[c] = be[c] - m * s;
    }
}

// layers 1,2: write bf16 into XC cols [0,128)
__global__ void k_bnapply_mid(const float* __restrict__ OUT,
                              const float* __restrict__ scale,
                              const float* __restrict__ shift, b16* __restrict__ XC) {
    int i = blockIdx.x * blockDim.x + threadIdx.x;
    if (i >= NN * 64) return;
    int row = i >> 6, c = (i & 63) * 2;
    float2 v = *(const float2*)&OUT[(size_t)row * 128 + c];
    float a = fmaf(v.x, scale[c], shift[c]);
    float b = fmaf(v.y, scale[c + 1], shift[c + 1]);
    a = a > 0.f ? a : 0.01f * a;
    b = b > 0.f ? b : 0.01f * b;
    ushort2 o;
    o.x = f2bf(a);
    o.y = f2bf(b);
    *(ushort2*)&XC[(size_t)row * 512 + c] = o;
}

// layer 3: write d_out (fp32 or bf16 per flag), NC=64
__global__ void k_bnapply_last(const float* __restrict__ OUT,
                               const float* __restrict__ scale,
                               const float* __restrict__ shift, void* __restrict__ dout,
                               const int* __restrict__ flags) {
    int i = blockIdx.x * blockDim.x + threadIdx.x;
    if (i >= NN * 64) return;
    int c = i & 63;
    float v = fmaf(OUT[i], scale[c], shift[c]);
    v = v > 0.f ? v : 0.01f * v;
    if (flags[0])
        ((float*)dout)[i] = v;
    else
        ((b16*)dout)[i] = f2bf(v);
}

// ---------- driver ----------
#define PB_B1 0
#define PB_B2 128
#define PB_G1 256
#define PB_BE1 384
#define PB_G2 512
#define PB_BE2 640
#define PB_G3 768
#define PB_BE3 832
#define PB_SZ 896

extern "C" void kernel_launch(void* const* d_in, const int* in_sizes, int n_in,
                              void* d_out, int out_size, void* d_ws, size_t ws_size,
                              hipStream_t stream) {
    const void* y   = d_in[0];
    const void* ei  = d_in[1];
    const void* ea  = d_in[2];
    const void* W1  = d_in[3];
    const void* b1  = d_in[4];
    const void* g1  = d_in[5];
    const void* be1 = d_in[6];
    const void* W2  = d_in[7];
    const void* b2  = d_in[8];
    const void* g2  = d_in[9];
    const void* be2 = d_in[10];
    const void* W3  = d_in[11];
    const void* g3  = d_in[12];
    const void* be3 = d_in[13];

    char* w = (char*)d_ws;
    size_t used = 0;
    auto carve = [&](size_t bytes) -> char* {
        char* p = w + used;
        used += (bytes + 255) & ~(size_t)255;
        return p;
    };

    int* flags   = (int*)carve(16);
    int* src32   = (int*)carve((size_t)NE * 4);
    int* dst32   = (int*)carve((size_t)NE * 4);
    float* deg   = (float*)carve((size_t)NN * 4);
    int* cnt     = (int*)carve((size_t)NN * 4);
    int* rowptr  = (int*)carve((size_t)(NN + 1) * 4);
    int* cscan   = (int*)carve((size_t)NN * 4);
    int* bsum    = (int*)carve((size_t)SCAN_NB * 4);
    int* csrc    = (int*)carve((size_t)NE * 4);
    float* cw    = (float*)carve((size_t)NE * 4);
    float* PB    = (float*)carve(PB_SZ * 4);
    b16* Wp1     = (b16*)carve((size_t)512 * 128 * 2);
    b16* Wp2     = (b16*)carve((size_t)512 * 128 * 2);
    b16* Wp3     = (b16*)carve((size_t)512 * 64 * 2);
    float* OUT   = (float*)carve((size_t)NN * 128 * 4);
    float* gsum  = (float*)carve(128 * 4);
    float* gsq   = (float*)carve(128 * 4);
    float* scale = (float*)carve(128 * 4);
    float* shift = (float*)carve(128 * 4);
    b16* XC      = (b16*)carve((size_t)NN * 512 * 2);

    // ----- detection + param normalize + weight pack -----
    k_detect<<<1, 64, 0, stream>>>(y, ei, flags);
    auto cvt = [&](const void* in, float* out, int n) {
        k_cvt<<<(n + 127) / 128, 128, 0, stream>>>(in, out, n, flags);
    };
    cvt(b1, PB + PB_B1, 128);
    cvt(b2, PB + PB_B2, 128);
    cvt(g1, PB + PB_G1, 128);
    cvt(be1, PB + PB_BE1, 128);
    cvt(g2, PB + PB_G2, 128);
    cvt(be2, PB + PB_BE2, 128);
    cvt(g3, PB + PB_G3, 64);
    cvt(be3, PB + PB_BE3, 64);
    k_pack<<<(512 * 128 / 8 + 255) / 256, 256, 0, stream>>>(W1, Wp1, 128, flags);
    k_pack<<<(512 * 128 / 8 + 255) / 256, 256, 0, stream>>>(W2, Wp2, 128, flags);
    k_pack<<<(512 * 64 / 8 + 255) / 256, 256, 0, stream>>>(W3, Wp3, 64, flags);

    // ----- graph prep -----
    k_idx<<<(NE + 255) / 256, 256, 0, stream>>>(ei, src32, dst32, flags);
    hipMemsetAsync(deg, 0, (size_t)NN * 4, stream);
    hipMemsetAsync(cnt, 0, (size_t)NN * 4, stream);
    k_degcnt<<<(NE + 255) / 256, 256, 0, stream>>>(dst32, ea, deg, cnt, flags);
    k_dis<<<(NN + 255) / 256, 256, 0, stream>>>(deg);
    k_scan1<<<SCAN_NB, SCAN_B, 0, stream>>>(cnt, cscan, bsum);
    k_scan2<<<1, 64, 0, stream>>>(bsum);
    k_scan3<<<(NN + 255) / 256, 256, 0, stream>>>(cscan, bsum, rowptr);
    hipMemsetAsync(cnt, 0, (size_t)NN * 4, stream);
    k_fill<<<(NE + 255) / 256, 256, 0, stream>>>(src32, dst32, ea, deg, rowptr, cnt,
                                                 csrc, cw, flags);

    // ----- layers -----
    k_cast<<<(NN * 32 + 255) / 256, 256, 0, stream>>>(y, XC, flags);

    auto spmm = [&](int ci, int co) {
        k_spmm<<<(NN * 64 + 255) / 256, 256, 0, stream>>>(XC, ci, co, rowptr, csrc, cw);
    };
    const int gemm_grid = (NN + 127) / 128;

    auto layer = [&](const b16* Wp, const float* bias, const float* g, const float* be,
                     int NC, bool last) {
        spmm(0, 128);
        spmm(128, 256);
        spmm(256, 384);
        hipMemsetAsync(gsum, 0, NC * 4, stream);
        hipMemsetAsync(gsq, 0, NC * 4, stream);
        if (NC == 128)
            k_mgemm<128><<<gemm_grid, 256, 0, stream>>>(XC, Wp, bias, OUT, gsum, gsq);
        else
            k_mgemm<64><<<gemm_grid, 256, 0, stream>>>(XC, Wp, bias, OUT, gsum, gsq);
        k_bnparam<<<1, NC, 0, stream>>>(gsum, gsq, g, be, scale, shift, NC);
        if (last)
            k_bnapply_last<<<(NN * 64 + 255) / 256, 256, 0, stream>>>(OUT, scale, shift,
                                                                      d_out, flags);
        else
            k_bnapply_mid<<<(NN * 64 + 255) / 256, 256, 0, stream>>>(OUT, scale, shift,
                                                                     XC);
    };

    layer(Wp1, PB + PB_B1, PB + PB_G1, PB + PB_BE1, 128, false);
    layer(Wp2, PB + PB_B2, PB + PB_G2, PB + PB_BE2, 128, false);
    layer(Wp3, nullptr, PB + PB_G3, PB + PB_BE3, 64, true);
}

// Round 6
// 800.846 us; speedup vs baseline: 2.6156x; 1.0435x over previous
//
#include <hip/hip_runtime.h>
#include <hip/hip_bf16.h>

typedef unsigned short b16;
typedef __attribute__((ext_vector_type(8))) unsigned short us8;
typedef __attribute__((ext_vector_type(8))) short short8;   // MFMA A/B frag (8 bf16)
typedef __attribute__((ext_vector_type(4))) float float4v;  // MFMA C/D frag

#define NN 100000
#define NE 600000

__device__ __forceinline__ float bf2f(b16 u) {
    return __uint_as_float(((unsigned)u) << 16);
}
__device__ __forceinline__ b16 f2bf(float f) {
    unsigned x = __float_as_uint(f);
    return (b16)((x + 0x7fffu + ((x >> 16) & 1u)) >> 16);
}

// ---------- dtype detection: flags[0]=1 if float tensors fp32, flags[1]=1 if idx int64
__global__ void k_detect(const void* __restrict__ y, const void* __restrict__ ei,
                         int* __restrict__ flags) {
    if (threadIdx.x == 0 && blockIdx.x == 0) {
        const b16* p = (const b16*)y;
        int f32 = 0;
        for (int i = 0; i < 128; ++i) {
            float v = bf2f(p[i]);
            if (!(fabsf(v) < 1e4f)) { f32 = 1; break; }
        }
        flags[0] = f32;
        const long long* q = (const long long*)ei;
        int i64 = 1;
        for (int i = 0; i < 4; ++i) {
            long long v = q[i];
            if (v < 0 || v >= NN) i64 = 0;
        }
        flags[1] = i64;
    }
}

__global__ void k_cvt(const void* __restrict__ in, float* __restrict__ out, int n,
                      const int* __restrict__ flags) {
    int i = blockIdx.x * blockDim.x + threadIdx.x;
    if (i >= n) return;
    out[i] = flags[0] ? ((const float*)in)[i] : bf2f(((const b16*)in)[i]);
}

// ---------- edge_index normalize ----------
__global__ void k_idx(const void* __restrict__ ei, int* __restrict__ src32,
                      int* __restrict__ dst32, const int* __restrict__ flags) {
    int e = blockIdx.x * blockDim.x + threadIdx.x;
    if (e >= NE) return;
    int s, d;
    if (flags[1]) {
        const long long* p = (const long long*)ei;
        s = (int)p[e];
        d = (int)p[NE + e];
    } else {
        const int* p = (const int*)ei;
        s = p[e];
        d = p[NE + e];
    }
    src32[e] = ((unsigned)s < NN) ? s : 0;
    dst32[e] = ((unsigned)d < NN) ? d : 0;
}

// ---------- degree (weighted) + CSR count ----------
__global__ void k_degcnt(const int* __restrict__ dst, const void* __restrict__ ea,
                         float* __restrict__ deg, int* __restrict__ cnt,
                         const int* __restrict__ flags) {
    int e = blockIdx.x * blockDim.x + threadIdx.x;
    if (e >= NE) return;
    float w = flags[0] ? ((const float*)ea)[e] : bf2f(((const b16*)ea)[e]);
    int d = dst[e];
    unsafeAtomicAdd(&deg[d], w);
    atomicAdd(&cnt[d], 1);
}

__global__ void k_dis(float* deg) {
    int n = blockIdx.x * blockDim.x + threadIdx.x;
    if (n < NN) {
        float d = deg[n];
        deg[n] = (d > 0.f) ? rsqrtf(fmaxf(d, 1e-12f)) : 0.f;
    }
}

// ---------- 3-phase exclusive scan of cnt[NN] -> rowptr[NN+1] ----------
#define SCAN_B 1024
#define SCAN_NB ((NN + SCAN_B - 1) / SCAN_B)

__global__ __launch_bounds__(SCAN_B) void k_scan1(const int* __restrict__ cnt,
                                                  int* __restrict__ inc,
                                                  int* __restrict__ bsum) {
    __shared__ int s[SCAN_B];
    int i = blockIdx.x * SCAN_B + threadIdx.x;
    s[threadIdx.x] = (i < NN) ? cnt[i] : 0;
    __syncthreads();
    for (int off = 1; off < SCAN_B; off <<= 1) {
        int t = (threadIdx.x >= off) ? s[threadIdx.x - off] : 0;
        __syncthreads();
        s[threadIdx.x] += t;
        __syncthreads();
    }
    if (i < NN) inc[i] = s[threadIdx.x];
    if (threadIdx.x == SCAN_B - 1) bsum[blockIdx.x] = s[SCAN_B - 1];
}

__global__ void k_scan2(int* bsum) {
    if (threadIdx.x == 0 && blockIdx.x == 0) {
        int a = 0;
        for (int i = 0; i < SCAN_NB; ++i) {
            int t = bsum[i];
            bsum[i] = a;
            a += t;
        }
    }
}

__global__ void k_scan3(const int* __restrict__ inc, const int* __restrict__ bsum,
                        int* __restrict__ rowptr) {
    int i = blockIdx.x * blockDim.x + threadIdx.x;
    if (i == 0) rowptr[0] = 0;
    if (i < NN) rowptr[i + 1] = inc[i] + bsum[i / SCAN_B];
}

// ---------- fill CSR ----------
__global__ void k_fill(const int* __restrict__ src, const int* __restrict__ dst,
                       const void* __restrict__ ea, const float* __restrict__ dis,
                       const int* __restrict__ rowptr, int* __restrict__ fill,
                       int* __restrict__ csrc, float* __restrict__ cw,
                       const int* __restrict__ flags) {
    int e = blockIdx.x * blockDim.x + threadIdx.x;
    if (e >= NE) return;
    float a = flags[0] ? ((const float*)ea)[e] : bf2f(((const b16*)ea)[e]);
    int d = dst[e];
    int s = src[e];
    int pos = rowptr[d] + atomicAdd(&fill[d], 1);
    csrc[pos] = s;
    cw[pos] = dis[s] * a * dis[d];
}

// ---------- pack W (fp32/bf16 [512][NC]) into B-fragment order ----------
__global__ void k_pack(const void* __restrict__ W, b16* __restrict__ Wp, int NC,
                       const int* __restrict__ flags) {
    int f = blockIdx.x * blockDim.x + threadIdx.x;
    int total = 512 * NC / 8;
    if (f >= total) return;
    int lane = f & 63;
    int rest = f >> 6;
    int CT = NC >> 4;
    int ct = rest % CT, ks = rest / CT;
    int k0 = 32 * ks + (lane >> 4) * 8;
    int col = 16 * ct + (lane & 15);
    us8 v;
#pragma unroll
    for (int j = 0; j < 8; ++j) {
        float x = flags[0] ? ((const float*)W)[(size_t)(k0 + j) * NC + col]
                           : bf2f(((const b16*)W)[(size_t)(k0 + j) * NC + col]);
        v[j] = f2bf(x);
    }
    *(us8*)&Wp[(size_t)f * 8] = v;
}

// ---------- initial cast y -> XC cols [0,128) (bf16, row stride 512) ----------
__global__ void k_cast(const void* __restrict__ y, b16* __restrict__ XC,
                       const int* __restrict__ flags) {
    int i = blockIdx.x * blockDim.x + threadIdx.x;
    if (i >= NN * 32) return;
    int row = i >> 5, cg = i & 31;
    float4 v;
    if (flags[0]) {
        v = ((const float4*)y)[i];
    } else {
        ushort4 u = ((const ushort4*)y)[i];
        v = make_float4(bf2f(u.x), bf2f(u.y), bf2f(u.z), bf2f(u.w));
    }
    ushort4 o;
    o.x = f2bf(v.x); o.y = f2bf(v.y); o.z = f2bf(v.z); o.w = f2bf(v.w);
    *(ushort4*)&XC[(size_t)row * 512 + 4 * cg] = o;
}

// ---------- SpMM gather: cols [ci,ci+128) -> [co,co+128) ----------
// wave = 1 node; quarter-wave = 1 edge (16 lanes x us8 = 256B row segment);
// unroll x2 -> up to 8 edges (2KB) in flight per wave.
__global__ __launch_bounds__(256) void k_spmm(b16* __restrict__ XC, int ci, int co,
                                              const int* __restrict__ rowptr,
                                              const int* __restrict__ csrc,
                                              const float* __restrict__ cw) {
    int gid = blockIdx.x * blockDim.x + threadIdx.x;
    int node = gid >> 6;
    if (node >= NN) return;
    int lane = gid & 63;
    int grp = lane >> 4;  // edge slot 0..3
    int l15 = lane & 15;  // 16B chunk within 256B segment
    int beg = rowptr[node], end = rowptr[node + 1];

    float a0[8], a1[8];
#pragma unroll
    for (int j = 0; j < 8; ++j) {
        a0[j] = 0.f;
        a1[j] = 0.f;
    }
    int i = beg;
    for (; i + 7 < end; i += 8) {
        int e0 = i + grp, e1 = i + 4 + grp;
        int s0 = csrc[e0];
        float w0 = cw[e0];
        int s1 = csrc[e1];
        float w1 = cw[e1];
        us8 u0 = *(const us8*)&XC[(size_t)s0 * 512 + ci + 8 * l15];
        us8 u1 = *(const us8*)&XC[(size_t)s1 * 512 + ci + 8 * l15];
#pragma unroll
        for (int j = 0; j < 8; ++j) {
            a0[j] = fmaf(w0, bf2f(u0[j]), a0[j]);
            a1[j] = fmaf(w1, bf2f(u1[j]), a1[j]);
        }
    }
    for (; i < end; i += 4) {
        int e = i + grp;
        bool act = e < end;
        int ee = act ? e : (end - 1);
        float w = act ? cw[ee] : 0.f;
        int s = csrc[ee];
        us8 u = *(const us8*)&XC[(size_t)s * 512 + ci + 8 * l15];
#pragma unroll
        for (int j = 0; j < 8; ++j) a0[j] = fmaf(w, bf2f(u[j]), a0[j]);
    }
#pragma unroll
    for (int j = 0; j < 8; ++j) a0[j] += a1[j];
#pragma unroll
    for (int j = 0; j < 8; ++j) a0[j] += __shfl_xor(a0[j], 16);
#pragma unroll
    for (int j = 0; j < 8; ++j) a0[j] += __shfl_xor(a0[j], 32);
    if (grp == 0) {
        us8 o;
#pragma unroll
        for (int j = 0; j < 8; ++j) o[j] = f2bf(a0[j]);
        *(us8*)&XC[(size_t)node * 512 + co + 8 * l15] = o;
    }
}

// ---------- MFMA GEMM + fused BN-stat epilogue ----------
// OUT[NN x NC](bf16) = XC[NN x 512](bf16) @ Wp (+bias); col sums/sumsq -> gsum/gsq.
// 64 rows/block, 4 waves: wave w owns rows [64b+16w, 64b+16w+16) x all NC cols.
// Double-buffered LDS, ONE barrier per k-step.
template <int NC>
__global__ __launch_bounds__(256) void k_mgemm(const b16* __restrict__ XC,
                                               const b16* __restrict__ Wp,
                                               const float* __restrict__ bias,
                                               b16* __restrict__ OUT,
                                               float* __restrict__ gsum,
                                               float* __restrict__ gsq) {
    constexpr int CT = NC / 16;
    __shared__ b16 As[2][64 * 40];   // 64 rows x 32 k, stride 40
    __shared__ b16 Bs[2][CT * 512];  // one k-step of packed W
    __shared__ float csum[NC], csq[NC];
    const int tid = threadIdx.x;
    const int wave = tid >> 6;
    const int lane = tid & 63;
    const int row0 = blockIdx.x * 64;
    const int quad = lane >> 4;
    const int l15 = lane & 15;

    float4v acc[CT];
#pragma unroll
    for (int ct = 0; ct < CT; ++ct) acc[ct] = (float4v)(0.f);
    for (int i = tid; i < NC; i += 256) {
        csum[i] = 0.f;
        csq[i] = 0.f;
    }

    const int arow = tid >> 2;  // 0..63
    const int apart = tid & 3;  // us8 quarter of 32-k row
    int grow = row0 + arow;
    if (grow >= NN) grow = NN - 1;  // clamp; dead rows excluded from store/stats
    const b16* gA = XC + (size_t)grow * 512 + apart * 8;
    b16* lA0 = &As[0][arow * 40 + apart * 8];
    b16* lA1 = &As[1][arow * 40 + apart * 8];

    // stage k-step 0
    *(us8*)lA0 = *(const us8*)gA;
    {
        const us8* gB = (const us8*)Wp;
#pragma unroll
        for (int q = 0; q < CT * 64 / 256; ++q)
            ((us8*)Bs[0])[q * 256 + tid] = gB[q * 256 + tid];
    }

    for (int ks = 0; ks < 16; ++ks) {
        int buf = ks & 1;
        __syncthreads();
        if (ks < 15) {  // stage ks+1 into other buffer while computing ks
            *(us8*)(buf ? lA0 : lA1) = *(const us8*)(gA + 32 * (ks + 1));
            const us8* gB = (const us8*)(Wp + (size_t)(ks + 1) * CT * 512);
#pragma unroll
            for (int q = 0; q < CT * 64 / 256; ++q)
                ((us8*)Bs[buf ^ 1])[q * 256 + tid] = gB[q * 256 + tid];
        }
        short8 af = *(const short8*)&As[buf][(wave * 16 + l15) * 40 + quad * 8];
#pragma unroll
        for (int ct = 0; ct < CT; ++ct) {
            short8 bf = *(const short8*)&Bs[buf][ct * 512 + lane * 8];
            acc[ct] = __builtin_amdgcn_mfma_f32_16x16x32_bf16(af, bf, acc[ct], 0, 0, 0);
        }
    }

    // epilogue: bf16 store + BN stats (C/D: col=lane&15, row=quad*4+reg)
#pragma unroll
    for (int ct = 0; ct < CT; ++ct) {
        int col = 16 * ct + l15;
        float bv = bias ? bias[col] : 0.f;
        float s = 0.f, sq = 0.f;
#pragma unroll
        for (int r = 0; r < 4; ++r) {
            int row = row0 + wave * 16 + quad * 4 + r;
            if (row < NN) {
                float v = acc[ct][r] + bv;
                OUT[(size_t)row * NC + col] = f2bf(v);
                s += v;
                sq += v * v;
            }
        }
        s += __shfl_xor(s, 16);
        s += __shfl_xor(s, 32);
        sq += __shfl_xor(sq, 16);
        sq += __shfl_xor(sq, 32);
        if (quad == 0) {
            atomicAdd(&csum[col], s);
            atomicAdd(&csq[col], sq);
        }
    }
    __syncthreads();
    for (int i = tid; i < NC; i += 256) {
        unsafeAtomicAdd(&gsum[i], csum[i]);
        unsafeAtomicAdd(&gsq[i], csq[i]);
    }
}

// ---------- BatchNorm params ----------
__global__ void k_bnparam(const float* gsum, const float* gsq, const float* g,
                          const float* be, float* scale, float* shift, int ncols) {
    int c = threadIdx.x;
    if (c < ncols) {
        float m = gsum[c] * (1.f / NN);
        float v = gsq[c] * (1.f / NN) - m * m;
        v = fmaxf(v, 0.f);
        float s = rsqrtf(v + 1e-5f) * g[c];
        scale[c] = s;
        shift[c] = be[c] - m * s;
    }
}

// layers 1,2: write bf16 into XC cols [0,128)
__global__ void k_bnapply_mid(const b16* __restrict__ OUT,
                              const float* __restrict__ scale,
                              const float* __restrict__ shift, b16* __restrict__ XC) {
    int i = blockIdx.x * blockDim.x + threadIdx.x;
    if (i >= NN * 64) return;
    int row = i >> 6, c = (i & 63) * 2;
    ushort2 u = *(const ushort2*)&OUT[(size_t)row * 128 + c];
    float a = fmaf(bf2f(u.x), scale[c], shift[c]);
    float b = fmaf(bf2f(u.y), scale[c + 1], shift[c + 1]);
    a = a > 0.f ? a : 0.01f * a;
    b = b > 0.f ? b : 0.01f * b;
    ushort2 o;
    o.x = f2bf(a);
    o.y = f2bf(b);
    *(ushort2*)&XC[(size_t)row * 512 + c] = o;
}

// layer 3: write d_out (fp32 or bf16 per flag), NC=64
__global__ void k_bnapply_last(const b16* __restrict__ OUT,
                               const float* __restrict__ scale,
                               const float* __restrict__ shift, void* __restrict__ dout,
                               const int* __restrict__ flags) {
    int i = blockIdx.x * blockDim.x + threadIdx.x;
    if (i >= NN * 64) return;
    int c = i & 63;
    float v = fmaf(bf2f(OUT[i]), scale[c], shift[c]);
    v = v > 0.f ? v : 0.01f * v;
    if (flags[0])
        ((float*)dout)[i] = v;
    else
        ((b16*)dout)[i] = f2bf(v);
}

// ---------- driver ----------
#define PB_B1 0
#define PB_B2 128
#define PB_G1 256
#define PB_BE1 384
#define PB_G2 512
#define PB_BE2 640
#define PB_G3 768
#define PB_BE3 832
#define PB_SZ 896

extern "C" void kernel_launch(void* const* d_in, const int* in_sizes, int n_in,
                              void* d_out, int out_size, void* d_ws, size_t ws_size,
                              hipStream_t stream) {
    const void* y   = d_in[0];
    const void* ei  = d_in[1];
    const void* ea  = d_in[2];
    const void* W1  = d_in[3];
    const void* b1  = d_in[4];
    const void* g1  = d_in[5];
    const void* be1 = d_in[6];
    const void* W2  = d_in[7];
    const void* b2  = d_in[8];
    const void* g2  = d_in[9];
    const void* be2 = d_in[10];
    const void* W3  = d_in[11];
    const void* g3  = d_in[12];
    const void* be3 = d_in[13];

    char* w = (char*)d_ws;
    size_t used = 0;
    auto carve = [&](size_t bytes) -> char* {
        char* p = w + used;
        used += (bytes + 255) & ~(size_t)255;
        return p;
    };

    int* flags   = (int*)carve(16);
    int* src32   = (int*)carve((size_t)NE * 4);
    int* dst32   = (int*)carve((size_t)NE * 4);
    float* deg   = (float*)carve((size_t)NN * 4);
    int* cnt     = (int*)carve((size_t)NN * 4);
    int* rowptr  = (int*)carve((size_t)(NN + 1) * 4);
    int* cscan   = (int*)carve((size_t)NN * 4);
    int* bsum    = (int*)carve((size_t)SCAN_NB * 4);
    int* csrc    = (int*)carve((size_t)NE * 4);
    float* cw    = (float*)carve((size_t)NE * 4);
    float* PB    = (float*)carve(PB_SZ * 4);
    b16* Wp1     = (b16*)carve((size_t)512 * 128 * 2);
    b16* Wp2     = (b16*)carve((size_t)512 * 128 * 2);
    b16* Wp3     = (b16*)carve((size_t)512 * 64 * 2);
    b16* OUT     = (b16*)carve((size_t)NN * 128 * 2);
    float* gsum  = (float*)carve(128 * 4);
    float* gsq   = (float*)carve(128 * 4);
    float* scale = (float*)carve(128 * 4);
    float* shift = (float*)carve(128 * 4);
    b16* XC      = (b16*)carve((size_t)NN * 512 * 2);

    // ----- detection + param normalize + weight pack -----
    k_detect<<<1, 64, 0, stream>>>(y, ei, flags);
    auto cvt = [&](const void* in, float* out, int n) {
        k_cvt<<<(n + 127) / 128, 128, 0, stream>>>(in, out, n, flags);
    };
    cvt(b1, PB + PB_B1, 128);
    cvt(b2, PB + PB_B2, 128);
    cvt(g1, PB + PB_G1, 128);
    cvt(be1, PB + PB_BE1, 128);
    cvt(g2, PB + PB_G2, 128);
    cvt(be2, PB + PB_BE2, 128);
    cvt(g3, PB + PB_G3, 64);
    cvt(be3, PB + PB_BE3, 64);
    k_pack<<<(512 * 128 / 8 + 255) / 256, 256, 0, stream>>>(W1, Wp1, 128, flags);
    k_pack<<<(512 * 128 / 8 + 255) / 256, 256, 0, stream>>>(W2, Wp2, 128, flags);
    k_pack<<<(512 * 64 / 8 + 255) / 256, 256, 0, stream>>>(W3, Wp3, 64, flags);

    // ----- graph prep -----
    k_idx<<<(NE + 255) / 256, 256, 0, stream>>>(ei, src32, dst32, flags);
    hipMemsetAsync(deg, 0, (size_t)NN * 4, stream);
    hipMemsetAsync(cnt, 0, (size_t)NN * 4, stream);
    k_degcnt<<<(NE + 255) / 256, 256, 0, stream>>>(dst32, ea, deg, cnt, flags);
    k_dis<<<(NN + 255) / 256, 256, 0, stream>>>(deg);
    k_scan1<<<SCAN_NB, SCAN_B, 0, stream>>>(cnt, cscan, bsum);
    k_scan2<<<1, 64, 0, stream>>>(bsum);
    k_scan3<<<(NN + 255) / 256, 256, 0, stream>>>(cscan, bsum, rowptr);
    hipMemsetAsync(cnt, 0, (size_t)NN * 4, stream);
    k_fill<<<(NE + 255) / 256, 256, 0, stream>>>(src32, dst32, ea, deg, rowptr, cnt,
                                                 csrc, cw, flags);

    // ----- layers -----
    k_cast<<<(NN * 32 + 255) / 256, 256, 0, stream>>>(y, XC, flags);

    auto spmm = [&](int ci, int co) {
        k_spmm<<<(NN * 64 + 255) / 256, 256, 0, stream>>>(XC, ci, co, rowptr, csrc, cw);
    };
    const int gemm_grid = (NN + 63) / 64;

    auto layer = [&](const b16* Wp, const float* bias, const float* g, const float* be,
                     int NC, bool last) {
        spmm(0, 128);
        spmm(128, 256);
        spmm(256, 384);
        hipMemsetAsync(gsum, 0, NC * 4, stream);
        hipMemsetAsync(gsq, 0, NC * 4, stream);
        if (NC == 128)
            k_mgemm<128><<<gemm_grid, 256, 0, stream>>>(XC, Wp, bias, OUT, gsum, gsq);
        else
            k_mgemm<64><<<gemm_grid, 256, 0, stream>>>(XC, Wp, bias, OUT, gsum, gsq);
        k_bnparam<<<1, NC, 0, stream>>>(gsum, gsq, g, be, scale, shift, NC);
        if (last)
            k_bnapply_last<<<(NN * 64 + 255) / 256, 256, 0, stream>>>(OUT, scale, shift,
                                                                      d_out, flags);
        else
            k_bnapply_mid<<<(NN * 64 + 255) / 256, 256, 0, stream>>>(OUT, scale, shift,
                                                                     XC);
    };

    layer(Wp1, PB + PB_B1, PB + PB_G1, PB + PB_BE1, 128, false);
    layer(Wp2, PB + PB_B2, PB + PB_G2, PB + PB_BE2, 128, false);
    layer(Wp3, nullptr, PB + PB_G3, PB + PB_BE3, 64, true);
}

// Round 7
// 791.380 us; speedup vs baseline: 2.6469x; 1.0120x over previous
//
#include <hip/hip_runtime.h>
#include <hip/hip_bf16.h>

typedef unsigned short b16;
typedef __attribute__((ext_vector_type(8))) unsigned short us8;
typedef __attribute__((ext_vector_type(8))) short short8;   // MFMA A/B frag (8 bf16)
typedef __attribute__((ext_vector_type(4))) float float4v;  // MFMA C/D frag

#define NN 100000
#define NE 600000

__device__ __forceinline__ float bf2f(b16 u) {
    return __uint_as_float(((unsigned)u) << 16);
}
__device__ __forceinline__ b16 f2bf(float f) {
    unsigned x = __float_as_uint(f);
    return (b16)((x + 0x7fffu + ((x >> 16) & 1u)) >> 16);
}

// ---------- dtype detection: flags[0]=1 if float tensors fp32, flags[1]=1 if idx int64
__global__ void k_detect(const void* __restrict__ y, const void* __restrict__ ei,
                         int* __restrict__ flags) {
    if (threadIdx.x == 0 && blockIdx.x == 0) {
        const b16* p = (const b16*)y;
        int f32 = 0;
        for (int i = 0; i < 128; ++i) {
            float v = bf2f(p[i]);
            if (!(fabsf(v) < 1e4f)) { f32 = 1; break; }
        }
        flags[0] = f32;
        const long long* q = (const long long*)ei;
        int i64 = 1;
        for (int i = 0; i < 4; ++i) {
            long long v = q[i];
            if (v < 0 || v >= NN) i64 = 0;
        }
        flags[1] = i64;
    }
}

__global__ void k_cvt(const void* __restrict__ in, float* __restrict__ out, int n,
                      const int* __restrict__ flags) {
    int i = blockIdx.x * blockDim.x + threadIdx.x;
    if (i >= n) return;
    out[i] = flags[0] ? ((const float*)in)[i] : bf2f(((const b16*)in)[i]);
}

// ---------- edge_index normalize ----------
__global__ void k_idx(const void* __restrict__ ei, int* __restrict__ src32,
                      int* __restrict__ dst32, const int* __restrict__ flags) {
    int e = blockIdx.x * blockDim.x + threadIdx.x;
    if (e >= NE) return;
    int s, d;
    if (flags[1]) {
        const long long* p = (const long long*)ei;
        s = (int)p[e];
        d = (int)p[NE + e];
    } else {
        const int* p = (const int*)ei;
        s = p[e];
        d = p[NE + e];
    }
    src32[e] = ((unsigned)s < NN) ? s : 0;
    dst32[e] = ((unsigned)d < NN) ? d : 0;
}

// ---------- degree (weighted) + CSR count ----------
__global__ void k_degcnt(const int* __restrict__ dst, const void* __restrict__ ea,
                         float* __restrict__ deg, int* __restrict__ cnt,
                         const int* __restrict__ flags) {
    int e = blockIdx.x * blockDim.x + threadIdx.x;
    if (e >= NE) return;
    float w = flags[0] ? ((const float*)ea)[e] : bf2f(((const b16*)ea)[e]);
    int d = dst[e];
    unsafeAtomicAdd(&deg[d], w);
    atomicAdd(&cnt[d], 1);
}

__global__ void k_dis(float* deg) {
    int n = blockIdx.x * blockDim.x + threadIdx.x;
    if (n < NN) {
        float d = deg[n];
        deg[n] = (d > 0.f) ? rsqrtf(fmaxf(d, 1e-12f)) : 0.f;
    }
}

// ---------- 3-phase exclusive scan of cnt[NN] -> rowptr[NN+1] ----------
#define SCAN_B 1024
#define SCAN_NB ((NN + SCAN_B - 1) / SCAN_B)

__global__ __launch_bounds__(SCAN_B) void k_scan1(const int* __restrict__ cnt,
                                                  int* __restrict__ inc,
                                                  int* __restrict__ bsum) {
    __shared__ int s[SCAN_B];
    int i = blockIdx.x * SCAN_B + threadIdx.x;
    s[threadIdx.x] = (i < NN) ? cnt[i] : 0;
    __syncthreads();
    for (int off = 1; off < SCAN_B; off <<= 1) {
        int t = (threadIdx.x >= off) ? s[threadIdx.x - off] : 0;
        __syncthreads();
        s[threadIdx.x] += t;
        __syncthreads();
    }
    if (i < NN) inc[i] = s[threadIdx.x];
    if (threadIdx.x == SCAN_B - 1) bsum[blockIdx.x] = s[SCAN_B - 1];
}

__global__ void k_scan2(int* bsum) {
    if (threadIdx.x == 0 && blockIdx.x == 0) {
        int a = 0;
        for (int i = 0; i < SCAN_NB; ++i) {
            int t = bsum[i];
            bsum[i] = a;
            a += t;
        }
    }
}

__global__ void k_scan3(const int* __restrict__ inc, const int* __restrict__ bsum,
                        int* __restrict__ rowptr) {
    int i = blockIdx.x * blockDim.x + threadIdx.x;
    if (i == 0) rowptr[0] = 0;
    if (i < NN) rowptr[i + 1] = inc[i] + bsum[i / SCAN_B];
}

// ---------- fill CSR ----------
__global__ void k_fill(const int* __restrict__ src, const int* __restrict__ dst,
                       const void* __restrict__ ea, const float* __restrict__ dis,
                       const int* __restrict__ rowptr, int* __restrict__ fill,
                       int* __restrict__ csrc, float* __restrict__ cw,
                       const int* __restrict__ flags) {
    int e = blockIdx.x * blockDim.x + threadIdx.x;
    if (e >= NE) return;
    float a = flags[0] ? ((const float*)ea)[e] : bf2f(((const b16*)ea)[e]);
    int d = dst[e];
    int s = src[e];
    int pos = rowptr[d] + atomicAdd(&fill[d], 1);
    csrc[pos] = s;
    cw[pos] = dis[s] * a * dis[d];
}

// ---------- pack W (fp32/bf16 [512][NC]) into B-fragment order ----------
__global__ void k_pack(const void* __restrict__ W, b16* __restrict__ Wp, int NC,
                       const int* __restrict__ flags) {
    int f = blockIdx.x * blockDim.x + threadIdx.x;
    int total = 512 * NC / 8;
    if (f >= total) return;
    int lane = f & 63;
    int rest = f >> 6;
    int CT = NC >> 4;
    int ct = rest % CT, ks = rest / CT;
    int k0 = 32 * ks + (lane >> 4) * 8;
    int col = 16 * ct + (lane & 15);
    us8 v;
#pragma unroll
    for (int j = 0; j < 8; ++j) {
        float x = flags[0] ? ((const float*)W)[(size_t)(k0 + j) * NC + col]
                           : bf2f(((const b16*)W)[(size_t)(k0 + j) * NC + col]);
        v[j] = f2bf(x);
    }
    *(us8*)&Wp[(size_t)f * 8] = v;
}

// ---------- initial cast y -> XC cols [0,128) (bf16, row stride 512) ----------
__global__ void k_cast(const void* __restrict__ y, b16* __restrict__ XC,
                       const int* __restrict__ flags) {
    int i = blockIdx.x * blockDim.x + threadIdx.x;
    if (i >= NN * 32) return;
    int row = i >> 5, cg = i & 31;
    float4 v;
    if (flags[0]) {
        v = ((const float4*)y)[i];
    } else {
        ushort4 u = ((const ushort4*)y)[i];
        v = make_float4(bf2f(u.x), bf2f(u.y), bf2f(u.z), bf2f(u.w));
    }
    ushort4 o;
    o.x = f2bf(v.x); o.y = f2bf(v.y); o.z = f2bf(v.z); o.w = f2bf(v.w);
    *(ushort4*)&XC[(size_t)row * 512 + 4 * cg] = o;
}

// ---------- SpMM gather: cols [ci,ci+128) -> [co,co+128) ----------
// wave = 1 node; quarter-wave (16 lanes x us8) = 256B row segment per edge.
// Always-predicated 16-edge chunks: all 16 gathers issued before any FMA,
// OOB slots clamped to end-1 (dup row, L1-hit) with weight 0.
__global__ __launch_bounds__(256) void k_spmm(b16* __restrict__ XC, int ci, int co,
                                              const int* __restrict__ rowptr,
                                              const int* __restrict__ csrc,
                                              const float* __restrict__ cw) {
    int gid = blockIdx.x * blockDim.x + threadIdx.x;
    int node = gid >> 6;
    if (node >= NN) return;
    int lane = gid & 63;
    int grp = lane >> 4;  // edge slot 0..3
    int l15 = lane & 15;  // 16B chunk within 256B segment
    int beg = rowptr[node], end = rowptr[node + 1];

    float a0[8], a1[8];
#pragma unroll
    for (int j = 0; j < 8; ++j) {
        a0[j] = 0.f;
        a1[j] = 0.f;
    }
    for (int i = beg; i < end; i += 16) {
        int e0 = i + grp, e1 = i + 4 + grp, e2 = i + 8 + grp, e3 = i + 12 + grp;
        float w0 = (e0 < end) ? cw[e0] : 0.f;
        float w1 = (e1 < end) ? cw[e1] : 0.f;
        float w2 = (e2 < end) ? cw[e2] : 0.f;
        float w3 = (e3 < end) ? cw[e3] : 0.f;
        int lim = end - 1;
        int s0 = csrc[e0 < lim ? e0 : lim];
        int s1 = csrc[e1 < lim ? e1 : lim];
        int s2 = csrc[e2 < lim ? e2 : lim];
        int s3 = csrc[e3 < lim ? e3 : lim];
        us8 u0 = *(const us8*)&XC[(size_t)s0 * 512 + ci + 8 * l15];
        us8 u1 = *(const us8*)&XC[(size_t)s1 * 512 + ci + 8 * l15];
        us8 u2 = *(const us8*)&XC[(size_t)s2 * 512 + ci + 8 * l15];
        us8 u3 = *(const us8*)&XC[(size_t)s3 * 512 + ci + 8 * l15];
#pragma unroll
        for (int j = 0; j < 8; ++j) {
            a0[j] = fmaf(w0, bf2f(u0[j]), a0[j]);
            a1[j] = fmaf(w1, bf2f(u1[j]), a1[j]);
            a0[j] = fmaf(w2, bf2f(u2[j]), a0[j]);
            a1[j] = fmaf(w3, bf2f(u3[j]), a1[j]);
        }
    }
#pragma unroll
    for (int j = 0; j < 8; ++j) a0[j] += a1[j];
#pragma unroll
    for (int j = 0; j < 8; ++j) a0[j] += __shfl_xor(a0[j], 16);
#pragma unroll
    for (int j = 0; j < 8; ++j) a0[j] += __shfl_xor(a0[j], 32);
    if (grp == 0) {
        us8 o;
#pragma unroll
        for (int j = 0; j < 8; ++j) o[j] = f2bf(a0[j]);
        *(us8*)&XC[(size_t)node * 512 + co + 8 * l15] = o;
    }
}

// ---------- MFMA GEMM + fused BN-stat epilogue ----------
// OUT[NN x NC](bf16) = XC[NN x 512](bf16) @ Wp (+bias); col sums/sumsq -> gsum/gsq.
// NO LDS, NO barriers: A frags (16B contiguous) and packed-B frags loaded
// straight from global into registers, depth-1 prefetch. Wave owns 32 rows
// (2 row-tiles of 16) x all NC cols; block = 4 waves = 128 rows.
template <int NC>
__global__ __launch_bounds__(256) void k_mgemm(const b16* __restrict__ XC,
                                               const b16* __restrict__ Wp,
                                               const float* __restrict__ bias,
                                               b16* __restrict__ OUT,
                                               float* __restrict__ gsum,
                                               float* __restrict__ gsq) {
    constexpr int CT = NC / 16;
    __shared__ float csum[NC], csq[NC];
    const int tid = threadIdx.x;
    const int wave = tid >> 6;
    const int lane = tid & 63;
    const int quad = lane >> 4;
    const int l15 = lane & 15;
    const int rbase = blockIdx.x * 128 + wave * 32;

    for (int i = tid; i < NC; i += 256) {
        csum[i] = 0.f;
        csq[i] = 0.f;
    }

    float4v acc[2][CT];
#pragma unroll
    for (int rt = 0; rt < 2; ++rt)
#pragma unroll
        for (int ct = 0; ct < CT; ++ct) acc[rt][ct] = (float4v)(0.f);

    const b16* gA[2];
#pragma unroll
    for (int rt = 0; rt < 2; ++rt) {
        int r = rbase + 16 * rt + l15;
        if (r >= NN) r = NN - 1;  // clamp; dead rows excluded from store/stats
        gA[rt] = XC + (size_t)r * 512 + quad * 8;
    }
    const b16* gB = Wp + lane * 8;

    short8 afc[2], bfc[CT], afn[2], bfn[CT];
#pragma unroll
    for (int rt = 0; rt < 2; ++rt) afc[rt] = *(const short8*)(gA[rt]);
#pragma unroll
    for (int ct = 0; ct < CT; ++ct) bfc[ct] = *(const short8*)(gB + ct * 512);

    for (int ks = 0; ks < 16; ++ks) {
        if (ks < 15) {  // prefetch next k-step into regs (issues before MFMA waits)
#pragma unroll
            for (int rt = 0; rt < 2; ++rt)
                afn[rt] = *(const short8*)(gA[rt] + 32 * (ks + 1));
#pragma unroll
            for (int ct = 0; ct < CT; ++ct)
                bfn[ct] = *(const short8*)(gB + (size_t)((ks + 1) * CT + ct) * 512);
        }
#pragma unroll
        for (int rt = 0; rt < 2; ++rt)
#pragma unroll
            for (int ct = 0; ct < CT; ++ct)
                acc[rt][ct] = __builtin_amdgcn_mfma_f32_16x16x32_bf16(
                    afc[rt], bfc[ct], acc[rt][ct], 0, 0, 0);
        if (ks < 15) {
#pragma unroll
            for (int rt = 0; rt < 2; ++rt) afc[rt] = afn[rt];
#pragma unroll
            for (int ct = 0; ct < CT; ++ct) bfc[ct] = bfn[ct];
        }
    }

    // epilogue: bf16 store + BN stats (C/D: col=lane&15, row=quad*4+reg)
#pragma unroll
    for (int rt = 0; rt < 2; ++rt) {
#pragma unroll
        for (int ct = 0; ct < CT; ++ct) {
            int col = 16 * ct + l15;
            float bv = bias ? bias[col] : 0.f;
            float s = 0.f, sq = 0.f;
#pragma unroll
            for (int r = 0; r < 4; ++r) {
                int row = rbase + 16 * rt + quad * 4 + r;
                if (row < NN) {
                    float v = acc[rt][ct][r] + bv;
                    OUT[(size_t)row * NC + col] = f2bf(v);
                    s += v;
                    sq += v * v;
                }
            }
            s += __shfl_xor(s, 16);
            s += __shfl_xor(s, 32);
            sq += __shfl_xor(sq, 16);
            sq += __shfl_xor(sq, 32);
            if (quad == 0) {
                atomicAdd(&csum[col], s);
                atomicAdd(&csq[col], sq);
            }
        }
    }
    __syncthreads();
    for (int i = tid; i < NC; i += 256) {
        unsafeAtomicAdd(&gsum[i], csum[i]);
        unsafeAtomicAdd(&gsq[i], csq[i]);
    }
}

// ---------- BatchNorm params ----------
__global__ void k_bnparam(const float* gsum, const float* gsq, const float* g,
                          const float* be, float* scale, float* shift, int ncols) {
    int c = threadIdx.x;
    if (c < ncols) {
        float m = gsum[c] * (1.f / NN);
        float v = gsq[c] * (1.f / NN) - m * m;
        v = fmaxf(v, 0.f);
        float s = rsqrtf(v + 1e-5f) * g[c];
        scale[c] = s;
        shift[c] = be[c] - m * s;
    }
}

// layers 1,2: write bf16 into XC cols [0,128)
__global__ void k_bnapply_mid(const b16* __restrict__ OUT,
                              const float* __restrict__ scale,
                              const float* __restrict__ shift, b16* __restrict__ XC) {
    int i = blockIdx.x * blockDim.x + threadIdx.x;
    if (i >= NN * 64) return;
    int row = i >> 6, c = (i & 63) * 2;
    ushort2 u = *(const ushort2*)&OUT[(size_t)row * 128 + c];
    float a = fmaf(bf2f(u.x), scale[c], shift[c]);
    float b = fmaf(bf2f(u.y), scale[c + 1], shift[c + 1]);
    a = a > 0.f ? a : 0.01f * a;
    b = b > 0.f ? b : 0.01f * b;
    ushort2 o;
    o.x = f2bf(a);
    o.y = f2bf(b);
    *(ushort2*)&XC[(size_t)row * 512 + c] = o;
}

// layer 3: write d_out (fp32 or bf16 per flag), NC=64
__global__ void k_bnapply_last(const b16* __restrict__ OUT,
                               const float* __restrict__ scale,
                               const float* __restrict__ shift, void* __restrict__ dout,
                               const int* __restrict__ flags) {
    int i = blockIdx.x * blockDim.x + threadIdx.x;
    if (i >= NN * 64) return;
    int c = i & 63;
    float v = fmaf(bf2f(OUT[i]), scale[c], shift[c]);
    v = v > 0.f ? v : 0.01f * v;
    if (flags[0])
        ((float*)dout)[i] = v;
    else
        ((b16*)dout)[i] = f2bf(v);
}

// ---------- driver ----------
#define PB_B1 0
#define PB_B2 128
#define PB_G1 256
#define PB_BE1 384
#define PB_G2 512
#define PB_BE2 640
#define PB_G3 768
#define PB_BE3 832
#define PB_SZ 896

extern "C" void kernel_launch(void* const* d_in, const int* in_sizes, int n_in,
                              void* d_out, int out_size, void* d_ws, size_t ws_size,
                              hipStream_t stream) {
    const void* y   = d_in[0];
    const void* ei  = d_in[1];
    const void* ea  = d_in[2];
    const void* W1  = d_in[3];
    const void* b1  = d_in[4];
    const void* g1  = d_in[5];
    const void* be1 = d_in[6];
    const void* W2  = d_in[7];
    const void* b2  = d_in[8];
    const void* g2  = d_in[9];
    const void* be2 = d_in[10];
    const void* W3  = d_in[11];
    const void* g3  = d_in[12];
    const void* be3 = d_in[13];

    char* w = (char*)d_ws;
    size_t used = 0;
    auto carve = [&](size_t bytes) -> char* {
        char* p = w + used;
        used += (bytes + 255) & ~(size_t)255;
        return p;
    };

    int* flags   = (int*)carve(16);
    int* src32   = (int*)carve((size_t)NE * 4);
    int* dst32   = (int*)carve((size_t)NE * 4);
    float* deg   = (float*)carve((size_t)NN * 4);
    int* cnt     = (int*)carve((size_t)NN * 4);
    int* rowptr  = (int*)carve((size_t)(NN + 1) * 4);
    int* cscan   = (int*)carve((size_t)NN * 4);
    int* bsum    = (int*)carve((size_t)SCAN_NB * 4);
    int* csrc    = (int*)carve((size_t)NE * 4);
    float* cw    = (float*)carve((size_t)NE * 4);
    float* PB    = (float*)carve(PB_SZ * 4);
    b16* Wp1     = (b16*)carve((size_t)512 * 128 * 2);
    b16* Wp2     = (b16*)carve((size_t)512 * 128 * 2);
    b16* Wp3     = (b16*)carve((size_t)512 * 64 * 2);
    b16* OUT     = (b16*)carve((size_t)NN * 128 * 2);
    float* gsum  = (float*)carve(128 * 4);
    float* gsq   = (float*)carve(128 * 4);
    float* scale = (float*)carve(128 * 4);
    float* shift = (float*)carve(128 * 4);
    b16* XC      = (b16*)carve((size_t)NN * 512 * 2);

    // ----- detection + param normalize + weight pack -----
    k_detect<<<1, 64, 0, stream>>>(y, ei, flags);
    auto cvt = [&](const void* in, float* out, int n) {
        k_cvt<<<(n + 127) / 128, 128, 0, stream>>>(in, out, n, flags);
    };
    cvt(b1, PB + PB_B1, 128);
    cvt(b2, PB + PB_B2, 128);
    cvt(g1, PB + PB_G1, 128);
    cvt(be1, PB + PB_BE1, 128);
    cvt(g2, PB + PB_G2, 128);
    cvt(be2, PB + PB_BE2, 128);
    cvt(g3, PB + PB_G3, 64);
    cvt(be3, PB + PB_BE3, 64);
    k_pack<<<(512 * 128 / 8 + 255) / 256, 256, 0, stream>>>(W1, Wp1, 128, flags);
    k_pack<<<(512 * 128 / 8 + 255) / 256, 256, 0, stream>>>(W2, Wp2, 128, flags);
    k_pack<<<(512 * 64 / 8 + 255) / 256, 256, 0, stream>>>(W3, Wp3, 64, flags);

    // ----- graph prep -----
    k_idx<<<(NE + 255) / 256, 256, 0, stream>>>(ei, src32, dst32, flags);
    hipMemsetAsync(deg, 0, (size_t)NN * 4, stream);
    hipMemsetAsync(cnt, 0, (size_t)NN * 4, stream);
    k_degcnt<<<(NE + 255) / 256, 256, 0, stream>>>(dst32, ea, deg, cnt, flags);
    k_dis<<<(NN + 255) / 256, 256, 0, stream>>>(deg);
    k_scan1<<<SCAN_NB, SCAN_B, 0, stream>>>(cnt, cscan, bsum);
    k_scan2<<<1, 64, 0, stream>>>(bsum);
    k_scan3<<<(NN + 255) / 256, 256, 0, stream>>>(cscan, bsum, rowptr);
    hipMemsetAsync(cnt, 0, (size_t)NN * 4, stream);
    k_fill<<<(NE + 255) / 256, 256, 0, stream>>>(src32, dst32, ea, deg, rowptr, cnt,
                                                 csrc, cw, flags);

    // ----- layers -----
    k_cast<<<(NN * 32 + 255) / 256, 256, 0, stream>>>(y, XC, flags);

    auto spmm = [&](int ci, int co) {
        k_spmm<<<(NN * 64 + 255) / 256, 256, 0, stream>>>(XC, ci, co, rowptr, csrc, cw);
    };
    const int gemm_grid = (NN + 127) / 128;

    auto layer = [&](const b16* Wp, const float* bias, const float* g, const float* be,
                     int NC, bool last) {
        spmm(0, 128);
        spmm(128, 256);
        spmm(256, 384);
        hipMemsetAsync(gsum, 0, NC * 4, stream);
        hipMemsetAsync(gsq, 0, NC * 4, stream);
        if (NC == 128)
            k_mgemm<128><<<gemm_grid, 256, 0, stream>>>(XC, Wp, bias, OUT, gsum, gsq);
        else
            k_mgemm<64><<<gemm_grid, 256, 0, stream>>>(XC, Wp, bias, OUT, gsum, gsq);
        k_bnparam<<<1, NC, 0, stream>>>(gsum, gsq, g, be, scale, shift, NC);
        if (last)
            k_bnapply_last<<<(NN * 64 + 255) / 256, 256, 0, stream>>>(OUT, scale, shift,
                                                                      d_out, flags);
        else
            k_bnapply_mid<<<(NN * 64 + 255) / 256, 256, 0, stream>>>(OUT, scale, shift,
                                                                     XC);
    };

    layer(Wp1, PB + PB_B1, PB + PB_G1, PB + PB_BE1, 128, false);
    layer(Wp2, PB + PB_B2, PB + PB_G2, PB + PB_BE2, 128, false);
    layer(Wp3, nullptr, PB + PB_G3, PB + PB_BE3, 64, true);
}